// Round 5
// baseline (1040.539 us; speedup 1.0000x reference)
//
#include <hip/hip_runtime.h>

typedef unsigned short u16;
typedef short bf16x8 __attribute__((ext_vector_type(8)));
typedef float f32x4 __attribute__((ext_vector_type(4)));

#define BSZ 8192
#define OUTLD 7168

#define BAR_()  __builtin_amdgcn_s_barrier()
#define PIN_()  __builtin_amdgcn_sched_barrier(0)
#define LGKM0_() asm volatile("s_waitcnt lgkmcnt(0)" ::: "memory")
#define VM0_()   asm volatile("s_waitcnt vmcnt(0)" ::: "memory")
#define VMC4_()  asm volatile("s_waitcnt vmcnt(4)" ::: "memory")

__device__ __forceinline__ u16 f2bf(float f) {
  union { float f; unsigned u; } v; v.f = f;
  unsigned r = v.u + 0x7FFFu + ((v.u >> 16) & 1u);
  return (u16)(r >> 16);
}
__device__ __forceinline__ float bf2f(u16 h) {
  union { unsigned u; float f; } v; v.u = ((unsigned)h) << 16;
  return v.f;
}
__device__ __forceinline__ float sigmoidf_(float x) { return 1.0f / (1.0f + __expf(-x)); }

__device__ __forceinline__ void gload16(const u16* g, u16* l) {
  __builtin_amdgcn_global_load_lds(
      (const __attribute__((address_space(1))) void*)g,
      (__attribute__((address_space(3))) void*)l, 16, 0, 0);
}

// ---- is_first dtype detection ----
__global__ void k_detect(const unsigned* __restrict__ isf, int* __restrict__ flag) {
  __shared__ unsigned red;
  if (threadIdx.x == 0) red = 0u;
  __syncthreads();
  unsigned v = 0;
  for (int i = threadIdx.x; i < 2048; i += 256) v |= isf[i];
  atomicOr(&red, v);
  __syncthreads();
  if (threadIdx.x == 0)
    *flag = (((red & 0xFFFFFF00u) != 0u) && ((red & 0xFEFEFEFEu) == 0u)) ? 1 : 0;
}

__device__ __forceinline__ bool is_first_row(const void* isf, int fl, int b) {
  return fl ? (((const unsigned char*)isf)[b] != 0) : (((const int*)isf)[b] != 0);
}

// ---- f32 -> bf16 convert, optional per-row is_first zeroing ----
__global__ void k_reset_cvt(const float* __restrict__ src, u16* __restrict__ dst,
                            const void* __restrict__ isf, const int* __restrict__ flag,
                            int c4, long n4, int doReset) {
  int fl = flag ? *flag : 0;
  long stride = (long)gridDim.x * blockDim.x;
  for (long i = blockIdx.x * (long)blockDim.x + threadIdx.x; i < n4; i += stride) {
    float4 v = ((const float4*)src)[i];
    if (doReset && is_first_row(isf, fl, (int)(i / c4))) { v.x = v.y = v.z = v.w = 0.f; }
    ushort4 o; o.x = f2bf(v.x); o.y = f2bf(v.y); o.z = f2bf(v.z); o.w = f2bf(v.w);
    ((ushort4*)dst)[i] = o;
  }
}

// ---- GRU weight cvt with gate-interleave row permutation ----
// dst row (within blk): rP = (s>>4)*48 + g*16 + (s&15), from src row g*512+s.
__global__ void k_cvt_gruW(const float* __restrict__ src, u16* __restrict__ dst,
                           int ldk, long n8) {
  long stride = (long)gridDim.x * blockDim.x;
  int kc = ldk >> 3;
  for (long i = blockIdx.x * (long)blockDim.x + threadIdx.x; i < n8; i += stride) {
    int j = (int)(i % kc); long row = i / kc;
    long blk = row / 1536; int rP = (int)(row % 1536);
    int sHi = rP / 48, rem = rP % 48, g = rem >> 4, sLo = rem & 15;
    int srow = g * 512 + sHi * 16 + sLo;
    const float* s = src + (blk * 1536 + srow) * (long)ldk + j * 8;
    float4 v0 = ((const float4*)s)[0], v1 = ((const float4*)s)[1];
    ushort4 o0; o0.x = f2bf(v0.x); o0.y = f2bf(v0.y); o0.z = f2bf(v0.z); o0.w = f2bf(v0.w);
    ushort4 o1; o1.x = f2bf(v1.x); o1.y = f2bf(v1.y); o1.z = f2bf(v1.z); o1.w = f2bf(v1.w);
    ((ushort4*)(dst + i * 8))[0] = o0;
    ((ushort4*)(dst + i * 8))[1] = o1;
  }
}

// ---- action normalize + tiny K=8 encoder -> x[:, 0:1024] ----
__global__ void k_ae(const float* __restrict__ act, const float* __restrict__ Wact,
                     const float* __restrict__ bact, u16* __restrict__ x) {
  long stride = (long)gridDim.x * blockDim.x;
  for (long t = blockIdx.x * (long)blockDim.x + threadIdx.x; t < (long)BSZ * 256; t += stride) {
    int b = (int)(t >> 8), h0 = (int)(t & 255) * 4;
    float4 a0 = ((const float4*)act)[b * 2];
    float4 a1 = ((const float4*)act)[b * 2 + 1];
    float mag = fmaxf(
        fmaxf(fmaxf(fabsf(a0.x), fabsf(a0.y)), fmaxf(fabsf(a0.z), fabsf(a0.w))),
        fmaxf(fmaxf(fabsf(a1.x), fabsf(a1.y)), fmaxf(fabsf(a1.z), fabsf(a1.w))));
    float inv = 1.0f / fmaxf(mag, 1.0f);
    ushort4 o;
    u16* op = (u16*)&o;
#pragma unroll
    for (int j = 0; j < 4; ++j) {
      int h = h0 + j;
      float4 w0 = ((const float4*)Wact)[h * 2];
      float4 w1 = ((const float4*)Wact)[h * 2 + 1];
      float dot = a0.x * w0.x + a0.y * w0.y + a0.z * w0.z + a0.w * w0.w
                + a1.x * w1.x + a1.y * w1.y + a1.z * w1.z + a1.w * w1.w;
      op[j] = f2bf(dot * inv + bact[h]);
    }
    *(ushort4*)&x[(long)b * 2048 + h0] = o;
  }
}

// ======== 256x256 8-wave pipelined GEMM, 3-deep A / 2-deep B, counted vmcnt ====
// NT form: A [M,K] row-major, W [N,K] row-major. C = A1@W1^T (+A2@W2^T) + bias.
// Grid: (m-tile fastest, n-tile, desc). Per tile t: P0/P1 issue B(t+1),
// P2/P3 issue A(t+2); boundary waits vmcnt(4) -> A(t+2) stays in flight.
struct GDesc {
  const u16* A1; const u16* A2;
  int lda1, lda2, K1, K2;
  const u16* W1; const u16* W2;
  int ldw1, ldw2;
  const float* bias;
  float* outF; int ldoF;
  u16* outB; int ldoB;
  int actSilu;
};

__global__ __launch_bounds__(512, 2) void gemm256(GDesc d0, GDesc d1) {
  const GDesc d = blockIdx.z ? d1 : d0;
  __shared__ __align__(16) u16 lsA[3 * 16384];
  __shared__ __align__(16) u16 lsB[2 * 16384];
  const int tid = threadIdx.x;
  const int wave = tid >> 6, lane = tid & 63;
  const int wm = wave >> 2, wn = wave & 3;
  const int lrow = lane & 15, lq = lane >> 4, lr7 = lane & 7;
  const int m0 = blockIdx.x * 256, n0 = blockIdx.y * 256;
  const int swz0 = (lq ^ lr7) * 8, swz1 = ((4 | lq) ^ lr7) * 8;
  const int sRow8 = lane >> 3;
  const int sCol = ((lane & 7) ^ sRow8) * 8;
  const int NT1 = d.K1 >> 6;
  const int NT = NT1 + (d.K2 >> 6);

  auto stageA = [&](int t, int rnd, int buf) {
    const int row = m0 + rnd * 64 + wave * 8 + sRow8;
    const u16* src = (t < NT1)
        ? d.A1 + (long)row * d.lda1 + t * 64 + sCol
        : d.A2 + (long)row * d.lda2 + (t - NT1) * 64 + sCol;
    gload16(src, &lsA[buf * 16384 + rnd * 4096 + wave * 512]);
  };
  auto stageB = [&](int t, int rnd, int buf) {
    const int row = n0 + rnd * 64 + wave * 8 + sRow8;
    const u16* src = (t < NT1)
        ? d.W1 + (long)row * d.ldw1 + t * 64 + sCol
        : d.W2 + (long)row * d.ldw2 + (t - NT1) * 64 + sCol;
    gload16(src, &lsB[buf * 16384 + rnd * 4096 + wave * 512]);
  };

  const f32x4 z4 = {0.f, 0.f, 0.f, 0.f};
  f32x4 acc[8][4];
#pragma unroll
  for (int m = 0; m < 8; ++m)
#pragma unroll
    for (int c = 0; c < 4; ++c) acc[m][c] = z4;

  // prologue: A(0)->a0, B(0)->b0, A(1)->a1; wait leaves A(1) in flight
#pragma unroll
  for (int r = 0; r < 4; ++r) stageA(0, r, 0);
#pragma unroll
  for (int r = 0; r < 4; ++r) stageB(0, r, 0);
#pragma unroll
  for (int r = 0; r < 4; ++r) stageA(1, r, 1);
  VMC4_(); BAR_(); PIN_();

  int ab = 0, bb = 0;   // A buf = t%3, B buf = t%2
#pragma unroll 1
  for (int t = 0; t < NT; ++t) {
    const int tn = t + 1;
    const int ab2 = (ab >= 1) ? ab - 1 : 2;   // (t+2)%3
    const u16* rA = lsA + ab * 16384 + (wm * 128 + lrow) * 64;
    const u16* rB = lsB + bb * 16384 + (wn * 64 + lrow) * 64;
    bf16x8 bf[4], af[4];
    // ---- P0: m0-3 x n0-3, kk0 | issue B(t+1) rounds 0-1
    if (tn < NT) { stageB(tn, 0, bb ^ 1); stageB(tn, 1, bb ^ 1); }
#pragma unroll
    for (int c = 0; c < 4; ++c) bf[c] = *(const bf16x8*)(rB + c * 1024 + swz0);
#pragma unroll
    for (int m = 0; m < 4; ++m) af[m] = *(const bf16x8*)(rA + m * 1024 + swz0);
    BAR_(); PIN_(); LGKM0_(); PIN_();
    __builtin_amdgcn_s_setprio(1);
#pragma unroll
    for (int m = 0; m < 4; ++m)
#pragma unroll
      for (int c = 0; c < 4; ++c)
        acc[m][c] = __builtin_amdgcn_mfma_f32_16x16x32_bf16(af[m], bf[c], acc[m][c], 0, 0, 0);
    __builtin_amdgcn_s_setprio(0);
    BAR_(); PIN_();
    // ---- P1: m4-7, kk0 | issue B(t+1) rounds 2-3
    if (tn < NT) { stageB(tn, 2, bb ^ 1); stageB(tn, 3, bb ^ 1); }
#pragma unroll
    for (int m = 0; m < 4; ++m) af[m] = *(const bf16x8*)(rA + (4 + m) * 1024 + swz0);
    BAR_(); PIN_(); LGKM0_(); PIN_();
    __builtin_amdgcn_s_setprio(1);
#pragma unroll
    for (int m = 0; m < 4; ++m)
#pragma unroll
      for (int c = 0; c < 4; ++c)
        acc[4 + m][c] = __builtin_amdgcn_mfma_f32_16x16x32_bf16(af[m], bf[c], acc[4 + m][c], 0, 0, 0);
    __builtin_amdgcn_s_setprio(0);
    BAR_(); PIN_();
    // ---- P2: m0-3, kk1 | issue A(t+2) rounds 0-1
    if (t + 2 < NT) { stageA(t + 2, 0, ab2); stageA(t + 2, 1, ab2); }
#pragma unroll
    for (int c = 0; c < 4; ++c) bf[c] = *(const bf16x8*)(rB + c * 1024 + swz1);
#pragma unroll
    for (int m = 0; m < 4; ++m) af[m] = *(const bf16x8*)(rA + m * 1024 + swz1);
    BAR_(); PIN_(); LGKM0_(); PIN_();
    __builtin_amdgcn_s_setprio(1);
#pragma unroll
    for (int m = 0; m < 4; ++m)
#pragma unroll
      for (int c = 0; c < 4; ++c)
        acc[m][c] = __builtin_amdgcn_mfma_f32_16x16x32_bf16(af[m], bf[c], acc[m][c], 0, 0, 0);
    __builtin_amdgcn_s_setprio(0);
    BAR_(); PIN_();
    // ---- P3: m4-7, kk1 | issue A(t+2) rounds 2-3; counted boundary wait
    if (t + 2 < NT) { stageA(t + 2, 2, ab2); stageA(t + 2, 3, ab2); }
#pragma unroll
    for (int m = 0; m < 4; ++m) af[m] = *(const bf16x8*)(rA + (4 + m) * 1024 + swz1);
    BAR_(); PIN_(); LGKM0_(); PIN_();
    __builtin_amdgcn_s_setprio(1);
#pragma unroll
    for (int m = 0; m < 4; ++m)
#pragma unroll
      for (int c = 0; c < 4; ++c)
        acc[4 + m][c] = __builtin_amdgcn_mfma_f32_16x16x32_bf16(af[m], bf[c], acc[4 + m][c], 0, 0, 0);
    __builtin_amdgcn_s_setprio(0);
    if (t + 2 < NT) { VMC4_(); } else { VM0_(); }
    BAR_(); PIN_();
    ab = (ab == 2) ? 0 : ab + 1;
    bb ^= 1;
  }

  // epilogue
#pragma unroll
  for (int c = 0; c < 4; ++c) {
    const int col = n0 + wn * 64 + c * 16 + lrow;
    const float bv = d.bias ? d.bias[col] : 0.f;
#pragma unroll
    for (int m = 0; m < 8; ++m) {
      const int rowb = m0 + wm * 128 + m * 16 + lq * 4;
#pragma unroll
      for (int r = 0; r < 4; ++r) {
        float v = acc[m][c][r] + bv;
        if (d.actSilu) v = v * sigmoidf_(v);
        if (d.outF) d.outF[(long)(rowb + r) * d.ldoF + col] = v;
        if (d.outB) d.outB[(long)(rowb + r) * d.ldoB + col] = f2bf(v);
      }
    }
  }
}

// ======== block-diagonal GRU, 256-row tile, 3-deep A / 2-deep W pipeline ========
__global__ __launch_bounds__(512, 2) void gru256(
    const u16* __restrict__ xbuf, const u16* __restrict__ hbuf,
    const u16* __restrict__ WihP, const u16* __restrict__ WhhP,
    const float* __restrict__ bih, const float* __restrict__ bhh,
    float* __restrict__ outF, u16* __restrict__ hnew)
{
  __shared__ __align__(16) u16 lsA[3 * 16384];
  __shared__ __align__(16) u16 lsW[2 * 12288];
  const int tid = threadIdx.x;
  const int wave = tid >> 6, lane = tid & 63;
  const int wm = wave >> 2, wn = wave & 3;
  const int lrow = lane & 15, lq = lane >> 4, lr7 = lane & 7;
  const int m0 = blockIdx.x * 256;        // m fastest: weight-tile L2 locality
  const int nt_ = blockIdx.y;             // 0..63
  const int blk = nt_ >> 3, stile = nt_ & 7;
  const int swz0 = (lq ^ lr7) * 8, swz1 = ((4 | lq) ^ lr7) * 8;
  const int sRow8 = lane >> 3;
  const int sCol = ((lane & 7) ^ sRow8) * 8;
  const int NT = 12;  // 4 x-tiles (K=256) + 8 h-tiles (K=512)

  auto stageA = [&](int t, int rnd, int buf) {
    const int row = m0 + rnd * 64 + wave * 8 + sRow8;
    const u16* src = (t < 4)
        ? xbuf + (long)row * 2048 + blk * 256 + t * 64 + sCol
        : hbuf + (long)row * 4096 + blk * 512 + (t - 4) * 64 + sCol;
    gload16(src, &lsA[buf * 16384 + rnd * 4096 + wave * 512]);
  };
  auto stageW = [&](int t, int rnd, int buf) {
    const long row = (long)blk * 1536 + stile * 192 + rnd * 64 + wave * 8 + sRow8;
    const u16* src = (t < 4)
        ? WihP + row * 256 + t * 64 + sCol
        : WhhP + row * 512 + (t - 4) * 64 + sCol;
    gload16(src, &lsW[buf * 12288 + rnd * 4096 + wave * 512]);
  };

  const f32x4 z4 = {0.f, 0.f, 0.f, 0.f};
  f32x4 acc[8][3];
#pragma unroll
  for (int m = 0; m < 8; ++m)
#pragma unroll
    for (int g = 0; g < 3; ++g) acc[m][g] = z4;

  // prologue
#pragma unroll
  for (int r = 0; r < 4; ++r) stageA(0, r, 0);
#pragma unroll
  for (int r = 0; r < 3; ++r) stageW(0, r, 0);
#pragma unroll
  for (int r = 0; r < 4; ++r) stageA(1, r, 1);
  VMC4_(); BAR_(); PIN_();

  int ab = 0, wb = 0;
#pragma unroll 1
  for (int t = 0; t < NT; ++t) {
    const int tn = t + 1;
    const int ab2 = (ab >= 1) ? ab - 1 : 2;
    const u16* rA = lsA + ab * 16384 + (wm * 128 + lrow) * 64;
    const u16* rW = lsW + wb * 12288 + (wn * 48 + lrow) * 64;
    bf16x8 wf[3], af[4];
    // ---- P0: m0-3 x g0-2, kk0 | issue W(t+1) rounds 0-1
    if (tn < NT) { stageW(tn, 0, wb ^ 1); stageW(tn, 1, wb ^ 1); }
#pragma unroll
    for (int g = 0; g < 3; ++g) wf[g] = *(const bf16x8*)(rW + g * 1024 + swz0);
#pragma unroll
    for (int m = 0; m < 4; ++m) af[m] = *(const bf16x8*)(rA + m * 1024 + swz0);
    BAR_(); PIN_(); LGKM0_(); PIN_();
    __builtin_amdgcn_s_setprio(1);
#pragma unroll
    for (int m = 0; m < 4; ++m)
#pragma unroll
      for (int g = 0; g < 3; ++g)
        acc[m][g] = __builtin_amdgcn_mfma_f32_16x16x32_bf16(af[m], wf[g], acc[m][g], 0, 0, 0);
    __builtin_amdgcn_s_setprio(0);
    BAR_(); PIN_();
    // ---- P1: m4-7, kk0 | issue W(t+1) round 2
    if (tn < NT) { stageW(tn, 2, wb ^ 1); }
#pragma unroll
    for (int m = 0; m < 4; ++m) af[m] = *(const bf16x8*)(rA + (4 + m) * 1024 + swz0);
    BAR_(); PIN_(); LGKM0_(); PIN_();
    __builtin_amdgcn_s_setprio(1);
#pragma unroll
    for (int m = 0; m < 4; ++m)
#pragma unroll
      for (int g = 0; g < 3; ++g)
        acc[4 + m][g] = __builtin_amdgcn_mfma_f32_16x16x32_bf16(af[m], wf[g], acc[4 + m][g], 0, 0, 0);
    __builtin_amdgcn_s_setprio(0);
    BAR_(); PIN_();
    // ---- P2: m0-3, kk1 | issue A(t+2) rounds 0-1
    if (t + 2 < NT) { stageA(t + 2, 0, ab2); stageA(t + 2, 1, ab2); }
#pragma unroll
    for (int g = 0; g < 3; ++g) wf[g] = *(const bf16x8*)(rW + g * 1024 + swz1);
#pragma unroll
    for (int m = 0; m < 4; ++m) af[m] = *(const bf16x8*)(rA + m * 1024 + swz1);
    BAR_(); PIN_(); LGKM0_(); PIN_();
    __builtin_amdgcn_s_setprio(1);
#pragma unroll
    for (int m = 0; m < 4; ++m)
#pragma unroll
      for (int g = 0; g < 3; ++g)
        acc[m][g] = __builtin_amdgcn_mfma_f32_16x16x32_bf16(af[m], wf[g], acc[m][g], 0, 0, 0);
    __builtin_amdgcn_s_setprio(0);
    BAR_(); PIN_();
    // ---- P3: m4-7, kk1 | issue A(t+2) rounds 2-3; counted boundary wait
    if (t + 2 < NT) { stageA(t + 2, 2, ab2); stageA(t + 2, 3, ab2); }
#pragma unroll
    for (int m = 0; m < 4; ++m) af[m] = *(const bf16x8*)(rA + (4 + m) * 1024 + swz1);
    BAR_(); PIN_(); LGKM0_(); PIN_();
    __builtin_amdgcn_s_setprio(1);
#pragma unroll
    for (int m = 0; m < 4; ++m)
#pragma unroll
      for (int g = 0; g < 3; ++g)
        acc[4 + m][g] = __builtin_amdgcn_mfma_f32_16x16x32_bf16(af[m], wf[g], acc[4 + m][g], 0, 0, 0);
    __builtin_amdgcn_s_setprio(0);
    if (t + 2 < NT) { VMC4_(); } else { VM0_(); }
    BAR_(); PIN_();
    ab = (ab == 2) ? 0 : ab + 1;
    wb ^= 1;
  }

  // fused GRU epilogue
  const int s = stile * 64 + wn * 16 + lrow;
  const int col = blk * 512 + s;
  const long bb = (long)blk * 1536 + s;
  const float br = bih[bb] + bhh[bb];
  const float bu = bih[bb + 512] + bhh[bb + 512];
  const float bc = bih[bb + 1024] + bhh[bb + 1024];
#pragma unroll
  for (int m = 0; m < 8; ++m) {
    const int rowb = m0 + wm * 128 + m * 16 + lq * 4;
#pragma unroll
    for (int r = 0; r < 4; ++r) {
      const int row = rowb + r;
      const float gr = acc[m][0][r] + br;
      const float gu = acc[m][1][r] + bu;
      const float gc = acc[m][2][r] + bc;
      const float rr = sigmoidf_(gr);
      const float uu = sigmoidf_(gu);
      const float cand = tanhf(rr * gc);
      const float h = bf2f(hbuf[(long)row * 4096 + col]);
      const float hn = (1.f - uu) * h + uu * cand;
      outF[(long)row * OUTLD + col] = hn;
      hnew[(long)row * 4096 + col] = f2bf(hn);
    }
  }
}

// ---- softmax over C=32 groups + unimix ----
__global__ void k_softmax(float* __restrict__ out) {
  int t = blockIdx.x * blockDim.x + threadIdx.x;
  if (t >= BSZ * 32) return;
  int b = t >> 5, g = t & 31;
  const float* src = out + (long)b * OUTLD + 4096 + g * 32;
  float* dst = out + (long)b * OUTLD + 5120 + g * 32;
  float v[32];
#pragma unroll
  for (int i = 0; i < 8; ++i) {
    float4 q = ((const float4*)src)[i];
    v[4 * i] = q.x; v[4 * i + 1] = q.y; v[4 * i + 2] = q.z; v[4 * i + 3] = q.w;
  }
  float m = v[0];
#pragma unroll
  for (int i = 1; i < 32; ++i) m = fmaxf(m, v[i]);
  float ssum = 0.f;
#pragma unroll
  for (int i = 0; i < 32; ++i) { v[i] = __expf(v[i] - m); ssum += v[i]; }
  float inv = 0.99f / ssum;
#pragma unroll
  for (int i = 0; i < 8; ++i) {
    float4 q;
    q.x = v[4 * i] * inv + 3.125e-4f;
    q.y = v[4 * i + 1] * inv + 3.125e-4f;
    q.z = v[4 * i + 2] * inv + 3.125e-4f;
    q.w = v[4 * i + 3] * inv + 3.125e-4f;
    ((float4*)dst)[i] = q;
  }
}

extern "C" void kernel_launch(void* const* d_in, const int* in_sizes, int n_in,
                              void* d_out, int out_size, void* d_ws, size_t ws_size,
                              hipStream_t stream) {
  const float* det   = (const float*)d_in[0];
  const float* stoch = (const float*)d_in[1];
  const float* pact  = (const float*)d_in[2];
  const float* embed = (const float*)d_in[3];
  const void*  isf   = d_in[4];
  const float* Wact  = (const float*)d_in[5];
  const float* bact  = (const float*)d_in[6];
  const float* Wst   = (const float*)d_in[7];
  const float* bst   = (const float*)d_in[8];
  const float* Wih   = (const float*)d_in[9];
  const float* bih   = (const float*)d_in[10];
  const float* Whh   = (const float*)d_in[11];
  const float* bhh   = (const float*)d_in[12];
  const float* Wpr1  = (const float*)d_in[13];
  const float* bpr1  = (const float*)d_in[14];
  const float* Wpr2  = (const float*)d_in[15];
  const float* bpr2  = (const float*)d_in[16];
  const float* Wpo1  = (const float*)d_in[17];
  const float* bpo1  = (const float*)d_in[18];
  const float* Wpo2  = (const float*)d_in[19];
  const float* bpo2  = (const float*)d_in[20];
  float* out = (float*)d_out;

  int* flag = (int*)d_ws;
  u16* wsu  = (u16*)((char*)d_ws + 256);
  u16* bWst  = wsu;                   // 1,048,576
  u16* bWihP = wsu + 1048576UL;       // 3,145,728 (permuted)
  u16* bWhhP = wsu + 4194304UL;       // 6,291,456 (permuted)
  u16* bWpr1 = wsu + 10485760UL;      // 4,194,304
  u16* bWpr2 = wsu + 14680064UL;      // 1,048,576
  u16* bWpo1 = wsu + 15728640UL;      // 5,242,880
  u16* bWpo2 = wsu + 20971520UL;      // 1,048,576
  u16* bufX  = wsu + 22020096UL;      // 16,777,216  [B,2048]
  u16* bufSt = wsu + 38797312UL;      // 8,388,608   stoch -> later ph
  u16* bufHb = wsu + 47185920UL;      // 33,554,432  hb -> later qh
  u16* bufHn = wsu + 80740352UL;      // 33,554,432  h_new bf16
  u16* bufEm = wsu + 114294784UL;     // 8,388,608   embed bf16

  k_detect<<<dim3(1), dim3(256), 0, stream>>>((const unsigned*)isf, flag);

  // plain weight conversions
  struct CV { const float* s; u16* d; long n; };
  CV cvs[5] = {
    {Wst, bWst, 1048576L}, {Wpr1, bWpr1, 4194304L}, {Wpr2, bWpr2, 1048576L},
    {Wpo1, bWpo1, 5242880L}, {Wpo2, bWpo2, 1048576L}
  };
  for (int i = 0; i < 5; ++i) {
    long n4 = cvs[i].n / 4;
    int blocks = (int)((n4 + 255) / 256); if (blocks > 4096) blocks = 4096;
    k_reset_cvt<<<dim3(blocks), dim3(256), 0, stream>>>(
        cvs[i].s, cvs[i].d, (const void*)nullptr, (const int*)nullptr, 1, n4, 0);
  }
  // permuted GRU weights
  k_cvt_gruW<<<dim3(1536), dim3(256), 0, stream>>>(Wih, bWihP, 256, 393216L);
  k_cvt_gruW<<<dim3(3072), dim3(256), 0, stream>>>(Whh, bWhhP, 512, 786432L);

  // input prep
  k_ae<<<dim3(2048), dim3(256), 0, stream>>>(pact, Wact, bact, bufX);
  k_reset_cvt<<<dim3(4096), dim3(256), 0, stream>>>(stoch, bufSt, isf, flag, 256, 2097152L, 1);
  k_reset_cvt<<<dim3(4096), dim3(256), 0, stream>>>(det, bufHb, isf, flag, 1024, 8388608L, 1);
  k_reset_cvt<<<dim3(4096), dim3(256), 0, stream>>>(embed, bufEm, (const void*)nullptr,
                                                    (const int*)nullptr, 256, 2097152L, 0);

  GDesc dSe;
  dSe.A1 = bufSt; dSe.A2 = nullptr; dSe.lda1 = 1024; dSe.lda2 = 0;
  dSe.K1 = 1024; dSe.K2 = 0;
  dSe.W1 = bWst; dSe.W2 = nullptr; dSe.ldw1 = 1024; dSe.ldw2 = 0;
  dSe.bias = bst; dSe.outF = nullptr; dSe.ldoF = 0;
  dSe.outB = bufX + 1024; dSe.ldoB = 2048; dSe.actSilu = 0;
  gemm256<<<dim3(32, 4, 1), dim3(512), 0, stream>>>(dSe, dSe);

  gru256<<<dim3(32, 64), dim3(512), 0, stream>>>(bufX, bufHb, bWihP, bWhhP,
                                                 bih, bhh, out, bufHn);

  GDesc dPr1, dPo1;
  dPr1.A1 = bufHn; dPr1.A2 = nullptr; dPr1.lda1 = 4096; dPr1.lda2 = 0;
  dPr1.K1 = 4096; dPr1.K2 = 0;
  dPr1.W1 = bWpr1; dPr1.W2 = nullptr; dPr1.ldw1 = 4096; dPr1.ldw2 = 0;
  dPr1.bias = bpr1; dPr1.outF = nullptr; dPr1.ldoF = 0;
  dPr1.outB = bufSt; dPr1.ldoB = 1024; dPr1.actSilu = 1;
  dPo1.A1 = bufHn; dPo1.A2 = bufEm; dPo1.lda1 = 4096; dPo1.lda2 = 1024;
  dPo1.K1 = 4096; dPo1.K2 = 1024;
  dPo1.W1 = bWpo1; dPo1.W2 = bWpo1 + 4096; dPo1.ldw1 = 5120; dPo1.ldw2 = 5120;
  dPo1.bias = bpo1; dPo1.outF = nullptr; dPo1.ldoF = 0;
  dPo1.outB = bufHb; dPo1.ldoB = 1024; dPo1.actSilu = 1;
  gemm256<<<dim3(32, 4, 2), dim3(512), 0, stream>>>(dPr1, dPo1);

  GDesc dPr2, dPo2;
  dPr2.A1 = bufSt; dPr2.A2 = nullptr; dPr2.lda1 = 1024; dPr2.lda2 = 0;
  dPr2.K1 = 1024; dPr2.K2 = 0;
  dPr2.W1 = bWpr2; dPr2.W2 = nullptr; dPr2.ldw1 = 1024; dPr2.ldw2 = 0;
  dPr2.bias = bpr2; dPr2.outF = out + 4096; dPr2.ldoF = OUTLD;
  dPr2.outB = nullptr; dPr2.ldoB = 0; dPr2.actSilu = 0;
  dPo2.A1 = bufHb; dPo2.A2 = nullptr; dPo2.lda1 = 1024; dPo2.lda2 = 0;
  dPo2.K1 = 1024; dPo2.K2 = 0;
  dPo2.W1 = bWpo2; dPo2.W2 = nullptr; dPo2.ldw1 = 1024; dPo2.ldw2 = 0;
  dPo2.bias = bpo2; dPo2.outF = out + 6144; dPo2.ldoF = OUTLD;
  dPo2.outB = nullptr; dPo2.ldoB = 0; dPo2.actSilu = 0;
  gemm256<<<dim3(32, 4, 2), dim3(512), 0, stream>>>(dPr2, dPo2);

  k_softmax<<<dim3(1024), dim3(256), 0, stream>>>(out);
}

// Round 6
// 854.413 us; speedup vs baseline: 1.2178x; 1.2178x over previous
//
#include <hip/hip_runtime.h>

typedef unsigned short u16;
typedef short bf16x8 __attribute__((ext_vector_type(8)));
typedef float f32x4 __attribute__((ext_vector_type(4)));

#define BSZ 8192
#define OUTLD 7168

#define BAR_()  __builtin_amdgcn_s_barrier()
#define PIN_()  __builtin_amdgcn_sched_barrier(0)
#define LGKM0_() asm volatile("s_waitcnt lgkmcnt(0)" ::: "memory")
#define VM0_()   asm volatile("s_waitcnt vmcnt(0)" ::: "memory")
#define VMC4_()  asm volatile("s_waitcnt vmcnt(4)" ::: "memory")

__device__ __forceinline__ u16 f2bf(float f) {
  union { float f; unsigned u; } v; v.f = f;
  unsigned r = v.u + 0x7FFFu + ((v.u >> 16) & 1u);
  return (u16)(r >> 16);
}
__device__ __forceinline__ float bf2f(u16 h) {
  union { unsigned u; float f; } v; v.u = ((unsigned)h) << 16;
  return v.f;
}
__device__ __forceinline__ float sigmoidf_(float x) { return 1.0f / (1.0f + __expf(-x)); }

__device__ __forceinline__ void gload16(const u16* g, u16* l) {
  __builtin_amdgcn_global_load_lds(
      (const __attribute__((address_space(1))) void*)g,
      (__attribute__((address_space(3))) void*)l, 16, 0, 0);
}

// ---- is_first dtype detection ----
__global__ void k_detect(const unsigned* __restrict__ isf, int* __restrict__ flag) {
  __shared__ unsigned red;
  if (threadIdx.x == 0) red = 0u;
  __syncthreads();
  unsigned v = 0;
  for (int i = threadIdx.x; i < 2048; i += 256) v |= isf[i];
  atomicOr(&red, v);
  __syncthreads();
  if (threadIdx.x == 0)
    *flag = (((red & 0xFFFFFF00u) != 0u) && ((red & 0xFEFEFEFEu) == 0u)) ? 1 : 0;
}

__device__ __forceinline__ bool is_first_row(const void* isf, int fl, int b) {
  return fl ? (((const unsigned char*)isf)[b] != 0) : (((const int*)isf)[b] != 0);
}

// ---- merged weight cvt: 7 plain f32->bf16 segments in one launch ----
struct Cv7 { const float* s[7]; u16* d[7]; long n4[7]; };
__global__ void k_cvtW(Cv7 c) {
  long stride = (long)gridDim.x * blockDim.x;
  long gid = blockIdx.x * (long)blockDim.x + threadIdx.x;
#pragma unroll 1
  for (int k = 0; k < 7; ++k) {
    const float4* src = (const float4*)c.s[k];
    ushort4* dst = (ushort4*)c.d[k];
    long n = c.n4[k];
    for (long i = gid; i < n; i += stride) {
      float4 v = src[i];
      ushort4 o; o.x = f2bf(v.x); o.y = f2bf(v.y); o.z = f2bf(v.z); o.w = f2bf(v.w);
      dst[i] = o;
    }
  }
}

// ---- merged input prep: stoch/det/embed cvt (+reset) in one launch ----
struct Prep3 { const float* s[3]; u16* d[3]; long n4[3]; int c4[3]; int doR[3]; };
__global__ void k_prep(Prep3 p, const void* __restrict__ isf, const int* __restrict__ flag) {
  int fl = *flag;
  long stride = (long)gridDim.x * blockDim.x;
  long gid = blockIdx.x * (long)blockDim.x + threadIdx.x;
#pragma unroll 1
  for (int k = 0; k < 3; ++k) {
    const float4* src = (const float4*)p.s[k];
    ushort4* dst = (ushort4*)p.d[k];
    long n = p.n4[k]; int c4 = p.c4[k], doR = p.doR[k];
    for (long i = gid; i < n; i += stride) {
      float4 v = src[i];
      if (doR && is_first_row(isf, fl, (int)(i / c4))) { v.x = v.y = v.z = v.w = 0.f; }
      ushort4 o; o.x = f2bf(v.x); o.y = f2bf(v.y); o.z = f2bf(v.z); o.w = f2bf(v.w);
      dst[i] = o;
    }
  }
}

// ---- action normalize + tiny K=8 encoder -> x[:, 0:1024] ----
__global__ void k_ae(const float* __restrict__ act, const float* __restrict__ Wact,
                     const float* __restrict__ bact, u16* __restrict__ x) {
  long stride = (long)gridDim.x * blockDim.x;
  for (long t = blockIdx.x * (long)blockDim.x + threadIdx.x; t < (long)BSZ * 256; t += stride) {
    int b = (int)(t >> 8), h0 = (int)(t & 255) * 4;
    float4 a0 = ((const float4*)act)[b * 2];
    float4 a1 = ((const float4*)act)[b * 2 + 1];
    float mag = fmaxf(
        fmaxf(fmaxf(fabsf(a0.x), fabsf(a0.y)), fmaxf(fabsf(a0.z), fabsf(a0.w))),
        fmaxf(fmaxf(fabsf(a1.x), fabsf(a1.y)), fmaxf(fabsf(a1.z), fabsf(a1.w))));
    float inv = 1.0f / fmaxf(mag, 1.0f);
    ushort4 o;
    u16* op = (u16*)&o;
#pragma unroll
    for (int j = 0; j < 4; ++j) {
      int h = h0 + j;
      float4 w0 = ((const float4*)Wact)[h * 2];
      float4 w1 = ((const float4*)Wact)[h * 2 + 1];
      float dot = a0.x * w0.x + a0.y * w0.y + a0.z * w0.z + a0.w * w0.w
                + a1.x * w1.x + a1.y * w1.y + a1.z * w1.z + a1.w * w1.w;
      op[j] = f2bf(dot * inv + bact[h]);
    }
    *(ushort4*)&x[(long)b * 2048 + h0] = o;
  }
}

struct GDesc {
  const u16* A1; const u16* A2;
  int lda1, lda2, K1, K2;
  const u16* W1; const u16* W2;
  int ldw1, ldw2;
  const float* bias;
  float* outF; int ldoF;
  u16* outB; int ldoB;
  int actSilu;
};

// ======== 128x128 2-barrier GEMM (R3-proven), swizzled, desc-select ========
__global__ __launch_bounds__(256) void gemm128(GDesc d0, GDesc d1) {
  const GDesc d = blockIdx.z ? d1 : d0;
  __shared__ __align__(16) u16 lsA[128 * 64];
  __shared__ __align__(16) u16 lsB[128 * 64];
  const int tid = threadIdx.x;
  const int wave = tid >> 6, lane = tid & 63;
  const int m0 = blockIdx.x * 128, n0 = blockIdx.y * 128;
  const int wr = (wave >> 1) * 64, wc = (wave & 1) * 64;
  const int lrow = lane & 15;
  const int lq = lane >> 4;
  const int lr7 = lrow & 7;
  const int grow = wave * 8 + (lane >> 3);
  const int gcol = ((lane & 7) ^ (lane >> 3)) * 8;
  const int ro0 = ((lq ^ lr7)) * 8;
  const int ro1 = (((4 | lq) ^ lr7)) * 8;

  const f32x4 z4 = {0.f, 0.f, 0.f, 0.f};
  f32x4 acc[4][4];
#pragma unroll
  for (int m = 0; m < 4; ++m)
#pragma unroll
    for (int c = 0; c < 4; ++c) acc[m][c] = z4;

#pragma unroll 1
  for (int phse = 0; phse < 2; ++phse) {
    const u16* A = phse ? d.A2 : d.A1;
    const u16* W = phse ? d.W2 : d.W1;
    const int lda = phse ? d.lda2 : d.lda1;
    const int ldw = phse ? d.ldw2 : d.ldw1;
    const int K = phse ? d.K2 : d.K1;
#pragma unroll 1
    for (int k0 = 0; k0 < K; k0 += 64) {
      __syncthreads();
#pragma unroll
      for (int i = 0; i < 4; ++i) {
        gload16(&A[(long)(m0 + i * 32 + grow) * lda + k0 + gcol], &lsA[i * 2048 + wave * 512]);
        gload16(&W[(long)(n0 + i * 32 + grow) * ldw + k0 + gcol], &lsB[i * 2048 + wave * 512]);
      }
      __syncthreads();
#pragma unroll
      for (int kk = 0; kk < 2; ++kk) {
        const int ro = kk ? ro1 : ro0;
        bf16x8 af[4], wfr[4];
#pragma unroll
        for (int m = 0; m < 4; ++m)
          af[m] = *(const bf16x8*)&lsA[(wr + m * 16 + lrow) * 64 + ro];
#pragma unroll
        for (int c = 0; c < 4; ++c)
          wfr[c] = *(const bf16x8*)&lsB[(wc + c * 16 + lrow) * 64 + ro];
#pragma unroll
        for (int m = 0; m < 4; ++m)
#pragma unroll
          for (int c = 0; c < 4; ++c)
            acc[m][c] = __builtin_amdgcn_mfma_f32_16x16x32_bf16(af[m], wfr[c], acc[m][c], 0, 0, 0);
      }
    }
  }

#pragma unroll
  for (int c = 0; c < 4; ++c) {
    const int col = n0 + wc + c * 16 + lrow;
    const float bv = d.bias ? d.bias[col] : 0.f;
#pragma unroll
    for (int m = 0; m < 4; ++m) {
      const int rowb = m0 + wr + m * 16 + (lane >> 4) * 4;
#pragma unroll
      for (int r = 0; r < 4; ++r) {
        float v = acc[m][c][r] + bv;
        if (d.actSilu) v = v * sigmoidf_(v);
        if (d.outF) d.outF[(long)(rowb + r) * d.ldoF + col] = v;
        if (d.outB) d.outB[(long)(rowb + r) * d.ldoB + col] = f2bf(v);
      }
    }
  }
}

// ======== block-diagonal GRU 128x64x3 (R3-proven), swizzled ========
__global__ __launch_bounds__(256) void gru128(
    const u16* __restrict__ xbuf, const u16* __restrict__ hbuf,
    const u16* __restrict__ Wih, const u16* __restrict__ Whh,
    const float* __restrict__ bih, const float* __restrict__ bhh,
    float* __restrict__ outF, u16* __restrict__ hnew)
{
  __shared__ __align__(16) u16 lsA[128 * 64];
  __shared__ __align__(16) u16 lsW[3 * 64 * 64];
  const int tid = threadIdx.x;
  const int wave = tid >> 6, lane = tid & 63;
  const int m0 = blockIdx.x * 128;
  const int blk = blockIdx.y >> 3;
  const int s0 = (blockIdx.y & 7) * 64;
  const int lrow = lane & 15;
  const int lq = lane >> 4;
  const int lr7 = lrow & 7;
  const int grow = wave * 8 + (lane >> 3);
  const int gcol = ((lane & 7) ^ (lane >> 3)) * 8;
  const int ro0 = ((lq ^ lr7)) * 8;
  const int ro1 = (((4 | lq) ^ lr7)) * 8;

  const f32x4 z4 = {0.f, 0.f, 0.f, 0.f};
  f32x4 acc[3][2][4];
#pragma unroll
  for (int g = 0; g < 3; ++g)
#pragma unroll
    for (int m = 0; m < 2; ++m)
#pragma unroll
      for (int c = 0; c < 4; ++c) acc[g][m][c] = z4;

#pragma unroll 1
  for (int phse = 0; phse < 2; ++phse) {
    const u16* A = phse ? (hbuf + blk * 512) : (xbuf + blk * 256);
    const u16* W = phse ? (Whh + (long)blk * 1536 * 512) : (Wih + (long)blk * 1536 * 256);
    const int lda = phse ? 4096 : 2048;
    const int ldw = phse ? 512 : 256;
    const int K = phse ? 512 : 256;
#pragma unroll 1
    for (int k0 = 0; k0 < K; k0 += 64) {
      __syncthreads();
#pragma unroll
      for (int i = 0; i < 4; ++i)
        gload16(&A[(long)(m0 + i * 32 + grow) * lda + k0 + gcol], &lsA[i * 2048 + wave * 512]);
#pragma unroll
      for (int j = 0; j < 6; ++j) {
        const int idx = j * 4 + wave;           // chunk 0..23
        const int off = idx * 512;
        const int g = off >> 12;
        const int r0 = (off & 4095) >> 6;
        gload16(&W[(long)(g * 512 + s0 + r0 + (lane >> 3)) * ldw + k0 + gcol], &lsW[off]);
      }
      __syncthreads();
#pragma unroll
      for (int kk = 0; kk < 2; ++kk) {
        const int ro = kk ? ro1 : ro0;
        bf16x8 af[2], wfr[3][4];
#pragma unroll
        for (int m = 0; m < 2; ++m)
          af[m] = *(const bf16x8*)&lsA[(wave * 32 + m * 16 + lrow) * 64 + ro];
#pragma unroll
        for (int g = 0; g < 3; ++g)
#pragma unroll
          for (int c = 0; c < 4; ++c)
            wfr[g][c] = *(const bf16x8*)&lsW[g * 4096 + (c * 16 + lrow) * 64 + ro];
#pragma unroll
        for (int g = 0; g < 3; ++g)
#pragma unroll
          for (int m = 0; m < 2; ++m)
#pragma unroll
            for (int c = 0; c < 4; ++c)
              acc[g][m][c] = __builtin_amdgcn_mfma_f32_16x16x32_bf16(af[m], wfr[g][c], acc[g][m][c], 0, 0, 0);
      }
    }
  }

#pragma unroll
  for (int c = 0; c < 4; ++c) {
    const int s = s0 + c * 16 + lrow;
    const int bb = blk * 1536 + s;
    const float br = bih[bb] + bhh[bb];
    const float bu = bih[bb + 512] + bhh[bb + 512];
    const float bc = bih[bb + 1024] + bhh[bb + 1024];
    const int hcol = blk * 512 + s;
#pragma unroll
    for (int m = 0; m < 2; ++m) {
      const int rowb = m0 + wave * 32 + m * 16 + (lane >> 4) * 4;
#pragma unroll
      for (int r = 0; r < 4; ++r) {
        const int row = rowb + r;
        const float gr = acc[0][m][c][r] + br;
        const float gu = acc[1][m][c][r] + bu;
        const float gc = acc[2][m][c][r] + bc;
        const float rr = sigmoidf_(gr);
        const float uu = sigmoidf_(gu);
        const float cand = tanhf(rr * gc);
        const float h = bf2f(hbuf[(long)row * 4096 + hcol]);
        const float hn = (1.f - uu) * h + uu * cand;
        outF[(long)row * OUTLD + hcol] = hn;
        hnew[(long)row * 4096 + hcol] = f2bf(hn);
      }
    }
  }
}

// ======== 256x256 8-wave pipelined GEMM (long-K regime: pr1/po1 only) ========
// 3-deep A / 2-deep B, counted vmcnt(4) at tile boundary, 1 block/CU, 256 blocks.
__global__ __launch_bounds__(512, 2) void gemm256(GDesc d0, GDesc d1) {
  const GDesc d = blockIdx.z ? d1 : d0;
  __shared__ __align__(16) u16 lsA[3 * 16384];
  __shared__ __align__(16) u16 lsB[2 * 16384];
  const int tid = threadIdx.x;
  const int wave = tid >> 6, lane = tid & 63;
  const int wm = wave >> 2, wn = wave & 3;
  const int lrow = lane & 15, lq = lane >> 4, lr7 = lane & 7;
  const int m0 = blockIdx.x * 256, n0 = blockIdx.y * 256;
  const int swz0 = (lq ^ lr7) * 8, swz1 = ((4 | lq) ^ lr7) * 8;
  const int sRow8 = lane >> 3;
  const int sCol = ((lane & 7) ^ sRow8) * 8;
  const int NT1 = d.K1 >> 6;
  const int NT = NT1 + (d.K2 >> 6);

  auto stageA = [&](int t, int rnd, int buf) {
    const int row = m0 + rnd * 64 + wave * 8 + sRow8;
    const u16* src = (t < NT1)
        ? d.A1 + (long)row * d.lda1 + t * 64 + sCol
        : d.A2 + (long)row * d.lda2 + (t - NT1) * 64 + sCol;
    gload16(src, &lsA[buf * 16384 + rnd * 4096 + wave * 512]);
  };
  auto stageB = [&](int t, int rnd, int buf) {
    const int row = n0 + rnd * 64 + wave * 8 + sRow8;
    const u16* src = (t < NT1)
        ? d.W1 + (long)row * d.ldw1 + t * 64 + sCol
        : d.W2 + (long)row * d.ldw2 + (t - NT1) * 64 + sCol;
    gload16(src, &lsB[buf * 16384 + rnd * 4096 + wave * 512]);
  };

  const f32x4 z4 = {0.f, 0.f, 0.f, 0.f};
  f32x4 acc[8][4];
#pragma unroll
  for (int m = 0; m < 8; ++m)
#pragma unroll
    for (int c = 0; c < 4; ++c) acc[m][c] = z4;

#pragma unroll
  for (int r = 0; r < 4; ++r) stageA(0, r, 0);
#pragma unroll
  for (int r = 0; r < 4; ++r) stageB(0, r, 0);
#pragma unroll
  for (int r = 0; r < 4; ++r) stageA(1, r, 1);
  VMC4_(); BAR_(); PIN_();

  int ab = 0, bb = 0;
#pragma unroll 1
  for (int t = 0; t < NT; ++t) {
    const int tn = t + 1;
    const int ab2 = (ab >= 1) ? ab - 1 : 2;
    const u16* rA = lsA + ab * 16384 + (wm * 128 + lrow) * 64;
    const u16* rB = lsB + bb * 16384 + (wn * 64 + lrow) * 64;
    bf16x8 bf[4], af[4];
    // P0
    if (tn < NT) { stageB(tn, 0, bb ^ 1); stageB(tn, 1, bb ^ 1); }
#pragma unroll
    for (int c = 0; c < 4; ++c) bf[c] = *(const bf16x8*)(rB + c * 1024 + swz0);
#pragma unroll
    for (int m = 0; m < 4; ++m) af[m] = *(const bf16x8*)(rA + m * 1024 + swz0);
    BAR_(); PIN_(); LGKM0_(); PIN_();
    __builtin_amdgcn_s_setprio(1);
#pragma unroll
    for (int m = 0; m < 4; ++m)
#pragma unroll
      for (int c = 0; c < 4; ++c)
        acc[m][c] = __builtin_amdgcn_mfma_f32_16x16x32_bf16(af[m], bf[c], acc[m][c], 0, 0, 0);
    __builtin_amdgcn_s_setprio(0);
    BAR_(); PIN_();
    // P1
    if (tn < NT) { stageB(tn, 2, bb ^ 1); stageB(tn, 3, bb ^ 1); }
#pragma unroll
    for (int m = 0; m < 4; ++m) af[m] = *(const bf16x8*)(rA + (4 + m) * 1024 + swz0);
    BAR_(); PIN_(); LGKM0_(); PIN_();
    __builtin_amdgcn_s_setprio(1);
#pragma unroll
    for (int m = 0; m < 4; ++m)
#pragma unroll
      for (int c = 0; c < 4; ++c)
        acc[4 + m][c] = __builtin_amdgcn_mfma_f32_16x16x32_bf16(af[m], bf[c], acc[4 + m][c], 0, 0, 0);
    __builtin_amdgcn_s_setprio(0);
    BAR_(); PIN_();
    // P2
    if (t + 2 < NT) { stageA(t + 2, 0, ab2); stageA(t + 2, 1, ab2); }
#pragma unroll
    for (int c = 0; c < 4; ++c) bf[c] = *(const bf16x8*)(rB + c * 1024 + swz1);
#pragma unroll
    for (int m = 0; m < 4; ++m) af[m] = *(const bf16x8*)(rA + m * 1024 + swz1);
    BAR_(); PIN_(); LGKM0_(); PIN_();
    __builtin_amdgcn_s_setprio(1);
#pragma unroll
    for (int m = 0; m < 4; ++m)
#pragma unroll
      for (int c = 0; c < 4; ++c)
        acc[m][c] = __builtin_amdgcn_mfma_f32_16x16x32_bf16(af[m], bf[c], acc[m][c], 0, 0, 0);
    __builtin_amdgcn_s_setprio(0);
    BAR_(); PIN_();
    // P3
    if (t + 2 < NT) { stageA(t + 2, 2, ab2); stageA(t + 2, 3, ab2); }
#pragma unroll
    for (int m = 0; m < 4; ++m) af[m] = *(const bf16x8*)(rA + (4 + m) * 1024 + swz1);
    BAR_(); PIN_(); LGKM0_(); PIN_();
    __builtin_amdgcn_s_setprio(1);
#pragma unroll
    for (int m = 0; m < 4; ++m)
#pragma unroll
      for (int c = 0; c < 4; ++c)
        acc[4 + m][c] = __builtin_amdgcn_mfma_f32_16x16x32_bf16(af[m], bf[c], acc[4 + m][c], 0, 0, 0);
    __builtin_amdgcn_s_setprio(0);
    if (t + 2 < NT) { VMC4_(); } else { VM0_(); }
    BAR_(); PIN_();
    ab = (ab == 2) ? 0 : ab + 1;
    bb ^= 1;
  }

#pragma unroll
  for (int c = 0; c < 4; ++c) {
    const int col = n0 + wn * 64 + c * 16 + lrow;
    const float bv = d.bias ? d.bias[col] : 0.f;
#pragma unroll
    for (int m = 0; m < 8; ++m) {
      const int rowb = m0 + wm * 128 + m * 16 + lq * 4;
#pragma unroll
      for (int r = 0; r < 4; ++r) {
        float v = acc[m][c][r] + bv;
        if (d.actSilu) v = v * sigmoidf_(v);
        if (d.outF) d.outF[(long)(rowb + r) * d.ldoF + col] = v;
        if (d.outB) d.outB[(long)(rowb + r) * d.ldoB + col] = f2bf(v);
      }
    }
  }
}

// ---- softmax over C=32 groups + unimix ----
__global__ void k_softmax(float* __restrict__ out) {
  int t = blockIdx.x * blockDim.x + threadIdx.x;
  if (t >= BSZ * 32) return;
  int b = t >> 5, g = t & 31;
  const float* src = out + (long)b * OUTLD + 4096 + g * 32;
  float* dst = out + (long)b * OUTLD + 5120 + g * 32;
  float v[32];
#pragma unroll
  for (int i = 0; i < 8; ++i) {
    float4 q = ((const float4*)src)[i];
    v[4 * i] = q.x; v[4 * i + 1] = q.y; v[4 * i + 2] = q.z; v[4 * i + 3] = q.w;
  }
  float m = v[0];
#pragma unroll
  for (int i = 1; i < 32; ++i) m = fmaxf(m, v[i]);
  float ssum = 0.f;
#pragma unroll
  for (int i = 0; i < 32; ++i) { v[i] = __expf(v[i] - m); ssum += v[i]; }
  float inv = 0.99f / ssum;
#pragma unroll
  for (int i = 0; i < 8; ++i) {
    float4 q;
    q.x = v[4 * i] * inv + 3.125e-4f;
    q.y = v[4 * i + 1] * inv + 3.125e-4f;
    q.z = v[4 * i + 2] * inv + 3.125e-4f;
    q.w = v[4 * i + 3] * inv + 3.125e-4f;
    ((float4*)dst)[i] = q;
  }
}

extern "C" void kernel_launch(void* const* d_in, const int* in_sizes, int n_in,
                              void* d_out, int out_size, void* d_ws, size_t ws_size,
                              hipStream_t stream) {
  const float* det   = (const float*)d_in[0];
  const float* stoch = (const float*)d_in[1];
  const float* pact  = (const float*)d_in[2];
  const float* embed = (const float*)d_in[3];
  const void*  isf   = d_in[4];
  const float* Wact  = (const float*)d_in[5];
  const float* bact  = (const float*)d_in[6];
  const float* Wst   = (const float*)d_in[7];
  const float* bst   = (const float*)d_in[8];
  const float* Wih   = (const float*)d_in[9];
  const float* bih   = (const float*)d_in[10];
  const float* Whh   = (const float*)d_in[11];
  const float* bhh   = (const float*)d_in[12];
  const float* Wpr1  = (const float*)d_in[13];
  const float* bpr1  = (const float*)d_in[14];
  const float* Wpr2  = (const float*)d_in[15];
  const float* bpr2  = (const float*)d_in[16];
  const float* Wpo1  = (const float*)d_in[17];
  const float* bpo1  = (const float*)d_in[18];
  const float* Wpo2  = (const float*)d_in[19];
  const float* bpo2  = (const float*)d_in[20];
  float* out = (float*)d_out;

  int* flag = (int*)d_ws;
  u16* wsu  = (u16*)((char*)d_ws + 256);
  u16* bWst  = wsu;                   // 1,048,576
  u16* bWih  = wsu + 1048576UL;       // 3,145,728
  u16* bWhh  = wsu + 4194304UL;       // 6,291,456
  u16* bWpr1 = wsu + 10485760UL;      // 4,194,304
  u16* bWpr2 = wsu + 14680064UL;      // 1,048,576
  u16* bWpo1 = wsu + 15728640UL;      // 5,242,880
  u16* bWpo2 = wsu + 20971520UL;      // 1,048,576
  u16* bufX  = wsu + 22020096UL;      // 16,777,216  [B,2048]
  u16* bufSt = wsu + 38797312UL;      // 8,388,608   stoch -> later ph
  u16* bufHb = wsu + 47185920UL;      // 33,554,432  hb -> later qh
  u16* bufHn = wsu + 80740352UL;      // 33,554,432  h_new bf16
  u16* bufEm = wsu + 114294784UL;     // 8,388,608   embed bf16

  k_detect<<<dim3(1), dim3(256), 0, stream>>>((const unsigned*)isf, flag);

  Cv7 cw;
  cw.s[0] = Wst;  cw.d[0] = bWst;  cw.n4[0] = 262144L;
  cw.s[1] = Wih;  cw.d[1] = bWih;  cw.n4[1] = 786432L;
  cw.s[2] = Whh;  cw.d[2] = bWhh;  cw.n4[2] = 1572864L;
  cw.s[3] = Wpr1; cw.d[3] = bWpr1; cw.n4[3] = 1048576L;
  cw.s[4] = Wpr2; cw.d[4] = bWpr2; cw.n4[4] = 262144L;
  cw.s[5] = Wpo1; cw.d[5] = bWpo1; cw.n4[5] = 1310720L;
  cw.s[6] = Wpo2; cw.d[6] = bWpo2; cw.n4[6] = 262144L;
  k_cvtW<<<dim3(4096), dim3(256), 0, stream>>>(cw);

  Prep3 pp;
  pp.s[0] = stoch; pp.d[0] = bufSt; pp.n4[0] = 2097152L; pp.c4[0] = 256;  pp.doR[0] = 1;
  pp.s[1] = det;   pp.d[1] = bufHb; pp.n4[1] = 8388608L; pp.c4[1] = 1024; pp.doR[1] = 1;
  pp.s[2] = embed; pp.d[2] = bufEm; pp.n4[2] = 2097152L; pp.c4[2] = 256;  pp.doR[2] = 0;
  k_prep<<<dim3(4096), dim3(256), 0, stream>>>(pp, isf, flag);

  k_ae<<<dim3(2048), dim3(256), 0, stream>>>(pact, Wact, bact, bufX);

  // se = stoch @ Wst^T + b -> x[:, 1024:2048]
  GDesc dSe;
  dSe.A1 = bufSt; dSe.A2 = nullptr; dSe.lda1 = 1024; dSe.lda2 = 0;
  dSe.K1 = 1024; dSe.K2 = 0;
  dSe.W1 = bWst; dSe.W2 = nullptr; dSe.ldw1 = 1024; dSe.ldw2 = 0;
  dSe.bias = bst; dSe.outF = nullptr; dSe.ldoF = 0;
  dSe.outB = bufX + 1024; dSe.ldoB = 2048; dSe.actSilu = 0;
  gemm128<<<dim3(64, 8, 1), dim3(256), 0, stream>>>(dSe, dSe);

  // GRU -> h_new (f32 to out cols [0,4096), bf16 to ws)
  gru128<<<dim3(64, 64), dim3(256), 0, stream>>>(bufX, bufHb, bWih, bWhh, bih, bhh, out, bufHn);

  // pr1 + po1 fused on the long-K pipelined kernel: 256 blocks = 1/CU
  GDesc dPr1, dPo1;
  dPr1.A1 = bufHn; dPr1.A2 = nullptr; dPr1.lda1 = 4096; dPr1.lda2 = 0;
  dPr1.K1 = 4096; dPr1.K2 = 0;
  dPr1.W1 = bWpr1; dPr1.W2 = nullptr; dPr1.ldw1 = 4096; dPr1.ldw2 = 0;
  dPr1.bias = bpr1; dPr1.outF = nullptr; dPr1.ldoF = 0;
  dPr1.outB = bufSt; dPr1.ldoB = 1024; dPr1.actSilu = 1;
  dPo1.A1 = bufHn; dPo1.A2 = bufEm; dPo1.lda1 = 4096; dPo1.lda2 = 1024;
  dPo1.K1 = 4096; dPo1.K2 = 1024;
  dPo1.W1 = bWpo1; dPo1.W2 = bWpo1 + 4096; dPo1.ldw1 = 5120; dPo1.ldw2 = 5120;
  dPo1.bias = bpo1; dPo1.outF = nullptr; dPo1.ldoF = 0;
  dPo1.outB = bufHb; dPo1.ldoB = 1024; dPo1.actSilu = 1;
  gemm256<<<dim3(32, 4, 2), dim3(512), 0, stream>>>(dPr1, dPo1);

  // pr2 + po2 fused on gemm128 (desc-select via z)
  GDesc dPr2, dPo2;
  dPr2.A1 = bufSt; dPr2.A2 = nullptr; dPr2.lda1 = 1024; dPr2.lda2 = 0;
  dPr2.K1 = 1024; dPr2.K2 = 0;
  dPr2.W1 = bWpr2; dPr2.W2 = nullptr; dPr2.ldw1 = 1024; dPr2.ldw2 = 0;
  dPr2.bias = bpr2; dPr2.outF = out + 4096; dPr2.ldoF = OUTLD;
  dPr2.outB = nullptr; dPr2.ldoB = 0; dPr2.actSilu = 0;
  dPo2.A1 = bufHb; dPo2.A2 = nullptr; dPo2.lda1 = 1024; dPo2.lda2 = 0;
  dPo2.K1 = 1024; dPo2.K2 = 0;
  dPo2.W1 = bWpo2; dPo2.W2 = nullptr; dPo2.ldw1 = 1024; dPo2.ldw2 = 0;
  dPo2.bias = bpo2; dPo2.outF = out + 6144; dPo2.ldoF = OUTLD;
  dPo2.outB = nullptr; dPo2.ldoB = 0; dPo2.actSilu = 0;
  gemm128<<<dim3(64, 8, 2), dim3(256), 0, stream>>>(dPr2, dPo2);

  k_softmax<<<dim3(1024), dim3(256), 0, stream>>>(out);
}

// Round 7
// 723.284 us; speedup vs baseline: 1.4386x; 1.1813x over previous
//
#include <hip/hip_runtime.h>

typedef unsigned short u16;
typedef short bf16x8 __attribute__((ext_vector_type(8)));
typedef float f32x4 __attribute__((ext_vector_type(4)));

#define BSZ 8192
#define OUTLD 7168

__device__ __forceinline__ u16 f2bf(float f) {
  union { float f; unsigned u; } v; v.f = f;
  unsigned r = v.u + 0x7FFFu + ((v.u >> 16) & 1u);
  return (u16)(r >> 16);
}
__device__ __forceinline__ float bf2f(u16 h) {
  union { unsigned u; float f; } v; v.u = ((unsigned)h) << 16;
  return v.f;
}
__device__ __forceinline__ float sigmoidf_(float x) { return 1.0f / (1.0f + __expf(-x)); }

__device__ __forceinline__ void gload16(const u16* g, u16* l) {
  __builtin_amdgcn_global_load_lds(
      (const __attribute__((address_space(1))) void*)g,
      (__attribute__((address_space(3))) void*)l, 16, 0, 0);
}

// ---- is_first dtype detection ----
__global__ void k_detect(const unsigned* __restrict__ isf, int* __restrict__ flag) {
  __shared__ unsigned red;
  if (threadIdx.x == 0) red = 0u;
  __syncthreads();
  unsigned v = 0;
  for (int i = threadIdx.x; i < 2048; i += 256) v |= isf[i];
  atomicOr(&red, v);
  __syncthreads();
  if (threadIdx.x == 0)
    *flag = (((red & 0xFFFFFF00u) != 0u) && ((red & 0xFEFEFEFEu) == 0u)) ? 1 : 0;
}

__device__ __forceinline__ bool is_first_row(const void* isf, int fl, int b) {
  return fl ? (((const unsigned char*)isf)[b] != 0) : (((const int*)isf)[b] != 0);
}

// ---- merged weight cvt: 7 f32->bf16 segments, flat index ----
struct Cv7 { const float* s[7]; u16* d[7]; long n4[7]; };
__global__ void k_cvtW(Cv7 c, long total4) {
  long stride = (long)gridDim.x * blockDim.x;
  for (long i = blockIdx.x * (long)blockDim.x + threadIdx.x; i < total4; i += stride) {
    long rem = i; int k = 0;
    while (k < 6 && rem >= c.n4[k]) { rem -= c.n4[k]; ++k; }
    float4 v = ((const float4*)c.s[k])[rem];
    ushort4 o; o.x = f2bf(v.x); o.y = f2bf(v.y); o.z = f2bf(v.z); o.w = f2bf(v.w);
    ((ushort4*)c.d[k])[rem] = o;
  }
}

// ---- merged input prep: stoch/det/embed cvt (+reset) ----
struct Prep3 { const float* s[3]; u16* d[3]; long n4[3]; int c4[3]; int doR[3]; };
__global__ void k_prep(Prep3 p, const void* __restrict__ isf, const int* __restrict__ flag) {
  int fl = *flag;
  long stride = (long)gridDim.x * blockDim.x;
  long gid = blockIdx.x * (long)blockDim.x + threadIdx.x;
#pragma unroll 1
  for (int k = 0; k < 3; ++k) {
    const float4* src = (const float4*)p.s[k];
    ushort4* dst = (ushort4*)p.d[k];
    long n = p.n4[k]; int c4 = p.c4[k], doR = p.doR[k];
    for (long i = gid; i < n; i += stride) {
      float4 v = src[i];
      if (doR && is_first_row(isf, fl, (int)(i / c4))) { v.x = v.y = v.z = v.w = 0.f; }
      ushort4 o; o.x = f2bf(v.x); o.y = f2bf(v.y); o.z = f2bf(v.z); o.w = f2bf(v.w);
      dst[i] = o;
    }
  }
}

// ---- action normalize + tiny K=8 encoder -> x[:, 0:1024] ----
__global__ void k_ae(const float* __restrict__ act, const float* __restrict__ Wact,
                     const float* __restrict__ bact, u16* __restrict__ x) {
  long stride = (long)gridDim.x * blockDim.x;
  for (long t = blockIdx.x * (long)blockDim.x + threadIdx.x; t < (long)BSZ * 256; t += stride) {
    int b = (int)(t >> 8), h0 = (int)(t & 255) * 4;
    float4 a0 = ((const float4*)act)[b * 2];
    float4 a1 = ((const float4*)act)[b * 2 + 1];
    float mag = fmaxf(
        fmaxf(fmaxf(fabsf(a0.x), fabsf(a0.y)), fmaxf(fabsf(a0.z), fabsf(a0.w))),
        fmaxf(fmaxf(fabsf(a1.x), fabsf(a1.y)), fmaxf(fabsf(a1.z), fabsf(a1.w))));
    float inv = 1.0f / fmaxf(mag, 1.0f);
    ushort4 o;
    u16* op = (u16*)&o;
#pragma unroll
    for (int j = 0; j < 4; ++j) {
      int h = h0 + j;
      float4 w0 = ((const float4*)Wact)[h * 2];
      float4 w1 = ((const float4*)Wact)[h * 2 + 1];
      float dot = a0.x * w0.x + a0.y * w0.y + a0.z * w0.z + a0.w * w0.w
                + a1.x * w1.x + a1.y * w1.y + a1.z * w1.z + a1.w * w1.w;
      op[j] = f2bf(dot * inv + bact[h]);
    }
    *(ushort4*)&x[(long)b * 2048 + h0] = o;
  }
}

struct GDesc {
  const u16* A1; const u16* A2;
  int lda1, lda2, K1, K2;
  const u16* W1; const u16* W2;
  int ldw1, ldw2;
  const float* bias;
  float* outF; int ldoF;
  u16* outB; int ldoB;
  int actSilu;
};

// ======== 128x128 2-barrier GEMM (R3-proven), swizzled, desc-select ========
__global__ __launch_bounds__(256, 3) void gemm128(GDesc d0, GDesc d1) {
  const GDesc d = blockIdx.z ? d1 : d0;
  __shared__ __align__(16) u16 lsA[128 * 64];
  __shared__ __align__(16) u16 lsB[128 * 64];
  const int tid = threadIdx.x;
  const int wave = tid >> 6, lane = tid & 63;
  const int m0 = blockIdx.x * 128, n0 = blockIdx.y * 128;
  const int wr = (wave >> 1) * 64, wc = (wave & 1) * 64;
  const int lrow = lane & 15;
  const int lq = lane >> 4;
  const int lr7 = lrow & 7;
  const int grow = wave * 8 + (lane >> 3);
  const int gcol = ((lane & 7) ^ (lane >> 3)) * 8;
  const int ro0 = ((lq ^ lr7)) * 8;
  const int ro1 = (((4 | lq) ^ lr7)) * 8;

  const f32x4 z4 = {0.f, 0.f, 0.f, 0.f};
  f32x4 acc[4][4];
#pragma unroll
  for (int m = 0; m < 4; ++m)
#pragma unroll
    for (int c = 0; c < 4; ++c) acc[m][c] = z4;

#pragma unroll 1
  for (int phse = 0; phse < 2; ++phse) {
    const u16* A = phse ? d.A2 : d.A1;
    const u16* W = phse ? d.W2 : d.W1;
    const int lda = phse ? d.lda2 : d.lda1;
    const int ldw = phse ? d.ldw2 : d.ldw1;
    const int K = phse ? d.K2 : d.K1;
#pragma unroll 1
    for (int k0 = 0; k0 < K; k0 += 64) {
      __syncthreads();
#pragma unroll
      for (int i = 0; i < 4; ++i) {
        gload16(&A[(long)(m0 + i * 32 + grow) * lda + k0 + gcol], &lsA[i * 2048 + wave * 512]);
        gload16(&W[(long)(n0 + i * 32 + grow) * ldw + k0 + gcol], &lsB[i * 2048 + wave * 512]);
      }
      __syncthreads();
#pragma unroll
      for (int kk = 0; kk < 2; ++kk) {
        const int ro = kk ? ro1 : ro0;
        bf16x8 af[4], wfr[4];
#pragma unroll
        for (int m = 0; m < 4; ++m)
          af[m] = *(const bf16x8*)&lsA[(wr + m * 16 + lrow) * 64 + ro];
#pragma unroll
        for (int c = 0; c < 4; ++c)
          wfr[c] = *(const bf16x8*)&lsB[(wc + c * 16 + lrow) * 64 + ro];
#pragma unroll
        for (int m = 0; m < 4; ++m)
#pragma unroll
          for (int c = 0; c < 4; ++c)
            acc[m][c] = __builtin_amdgcn_mfma_f32_16x16x32_bf16(af[m], wfr[c], acc[m][c], 0, 0, 0);
      }
    }
  }

#pragma unroll
  for (int c = 0; c < 4; ++c) {
    const int col = n0 + wc + c * 16 + lrow;
    const float bv = d.bias ? d.bias[col] : 0.f;
#pragma unroll
    for (int m = 0; m < 4; ++m) {
      const int rowb = m0 + wr + m * 16 + (lane >> 4) * 4;
#pragma unroll
      for (int r = 0; r < 4; ++r) {
        float v = acc[m][c][r] + bv;
        if (d.actSilu) v = v * sigmoidf_(v);
        if (d.outF) d.outF[(long)(rowb + r) * d.ldoF + col] = v;
        if (d.outB) d.outB[(long)(rowb + r) * d.ldoB + col] = f2bf(v);
      }
    }
  }
}

// ======== block-diagonal GRU, s-split 32-col tiles: acc 48 AGPR -> 3 waves/SIMD ====
__global__ __launch_bounds__(256, 3) void gru128(
    const u16* __restrict__ xbuf, const u16* __restrict__ hbuf,
    const u16* __restrict__ Wih, const u16* __restrict__ Whh,
    const float* __restrict__ bih, const float* __restrict__ bhh,
    float* __restrict__ outF, u16* __restrict__ hnew)
{
  __shared__ __align__(16) u16 lsA[128 * 64];
  __shared__ __align__(16) u16 lsW[3 * 32 * 64];
  const int tid = threadIdx.x;
  const int wave = tid >> 6, lane = tid & 63;
  const int m0 = blockIdx.x * 128;
  const int blk = blockIdx.y >> 4;
  const int s0 = (blockIdx.y & 15) * 32;
  const int lrow = lane & 15;
  const int lq = lane >> 4;
  const int lr7 = lrow & 7;
  const int grow = wave * 8 + (lane >> 3);
  const int gcol = ((lane & 7) ^ (lane >> 3)) * 8;
  const int ro0 = ((lq ^ lr7)) * 8;
  const int ro1 = (((4 | lq) ^ lr7)) * 8;

  const f32x4 z4 = {0.f, 0.f, 0.f, 0.f};
  f32x4 acc[3][2][2];
#pragma unroll
  for (int g = 0; g < 3; ++g)
#pragma unroll
    for (int m = 0; m < 2; ++m)
#pragma unroll
      for (int c = 0; c < 2; ++c) acc[g][m][c] = z4;

#pragma unroll 1
  for (int phse = 0; phse < 2; ++phse) {
    const u16* A = phse ? (hbuf + blk * 512) : (xbuf + blk * 256);
    const u16* W = phse ? (Whh + (long)blk * 1536 * 512) : (Wih + (long)blk * 1536 * 256);
    const int lda = phse ? 4096 : 2048;
    const int ldw = phse ? 512 : 256;
    const int K = phse ? 512 : 256;
#pragma unroll 1
    for (int k0 = 0; k0 < K; k0 += 64) {
      __syncthreads();
#pragma unroll
      for (int i = 0; i < 4; ++i)
        gload16(&A[(long)(m0 + i * 32 + grow) * lda + k0 + gcol], &lsA[i * 2048 + wave * 512]);
      // W tile: 3 gates x 32 rows x 64 cols = 12 chunks of 512 u16 (8 rows each)
#pragma unroll
      for (int j = 0; j < 3; ++j) {
        const int idx = j * 4 + wave;           // chunk 0..11
        const int off = idx * 512;
        const int g = idx >> 2;                 // gate
        const int r0 = (idx & 3) * 8;           // starting row within gate slice
        gload16(&W[(long)(g * 512 + s0 + r0 + (lane >> 3)) * ldw + k0 + gcol], &lsW[off]);
      }
      __syncthreads();
#pragma unroll
      for (int kk = 0; kk < 2; ++kk) {
        const int ro = kk ? ro1 : ro0;
        bf16x8 af[2], wfr[3][2];
#pragma unroll
        for (int m = 0; m < 2; ++m)
          af[m] = *(const bf16x8*)&lsA[(wave * 32 + m * 16 + lrow) * 64 + ro];
#pragma unroll
        for (int g = 0; g < 3; ++g)
#pragma unroll
          for (int c = 0; c < 2; ++c)
            wfr[g][c] = *(const bf16x8*)&lsW[g * 2048 + (c * 16 + lrow) * 64 + ro];
#pragma unroll
        for (int g = 0; g < 3; ++g)
#pragma unroll
          for (int m = 0; m < 2; ++m)
#pragma unroll
            for (int c = 0; c < 2; ++c)
              acc[g][m][c] = __builtin_amdgcn_mfma_f32_16x16x32_bf16(af[m], wfr[g][c], acc[g][m][c], 0, 0, 0);
      }
    }
  }

#pragma unroll
  for (int c = 0; c < 2; ++c) {
    const int s = s0 + c * 16 + lrow;
    const int bb = blk * 1536 + s;
    const float br = bih[bb] + bhh[bb];
    const float bu = bih[bb + 512] + bhh[bb + 512];
    const float bc = bih[bb + 1024] + bhh[bb + 1024];
    const int hcol = blk * 512 + s;
#pragma unroll
    for (int m = 0; m < 2; ++m) {
      const int rowb = m0 + wave * 32 + m * 16 + (lane >> 4) * 4;
#pragma unroll
      for (int r = 0; r < 4; ++r) {
        const int row = rowb + r;
        const float gr = acc[0][m][c][r] + br;
        const float gu = acc[1][m][c][r] + bu;
        const float gc = acc[2][m][c][r] + bc;
        const float rr = sigmoidf_(gr);
        const float uu = sigmoidf_(gu);
        const float cand = tanhf(rr * gc);
        const float h = bf2f(hbuf[(long)row * 4096 + hcol]);
        const float hn = (1.f - uu) * h + uu * cand;
        outF[(long)row * OUTLD + hcol] = hn;
        hnew[(long)row * 4096 + hcol] = f2bf(hn);
      }
    }
  }
}

// ---- softmax over C=32 groups + unimix ----
__global__ void k_softmax(float* __restrict__ out) {
  int t = blockIdx.x * blockDim.x + threadIdx.x;
  if (t >= BSZ * 32) return;
  int b = t >> 5, g = t & 31;
  const float* src = out + (long)b * OUTLD + 4096 + g * 32;
  float* dst = out + (long)b * OUTLD + 5120 + g * 32;
  float v[32];
#pragma unroll
  for (int i = 0; i < 8; ++i) {
    float4 q = ((const float4*)src)[i];
    v[4 * i] = q.x; v[4 * i + 1] = q.y; v[4 * i + 2] = q.z; v[4 * i + 3] = q.w;
  }
  float m = v[0];
#pragma unroll
  for (int i = 1; i < 32; ++i) m = fmaxf(m, v[i]);
  float ssum = 0.f;
#pragma unroll
  for (int i = 0; i < 32; ++i) { v[i] = __expf(v[i] - m); ssum += v[i]; }
  float inv = 0.99f / ssum;
#pragma unroll
  for (int i = 0; i < 8; ++i) {
    float4 q;
    q.x = v[4 * i] * inv + 3.125e-4f;
    q.y = v[4 * i + 1] * inv + 3.125e-4f;
    q.z = v[4 * i + 2] * inv + 3.125e-4f;
    q.w = v[4 * i + 3] * inv + 3.125e-4f;
    ((float4*)dst)[i] = q;
  }
}

extern "C" void kernel_launch(void* const* d_in, const int* in_sizes, int n_in,
                              void* d_out, int out_size, void* d_ws, size_t ws_size,
                              hipStream_t stream) {
  const float* det   = (const float*)d_in[0];
  const float* stoch = (const float*)d_in[1];
  const float* pact  = (const float*)d_in[2];
  const float* embed = (const float*)d_in[3];
  const void*  isf   = d_in[4];
  const float* Wact  = (const float*)d_in[5];
  const float* bact  = (const float*)d_in[6];
  const float* Wst   = (const float*)d_in[7];
  const float* bst   = (const float*)d_in[8];
  const float* Wih   = (const float*)d_in[9];
  const float* bih   = (const float*)d_in[10];
  const float* Whh   = (const float*)d_in[11];
  const float* bhh   = (const float*)d_in[12];
  const float* Wpr1  = (const float*)d_in[13];
  const float* bpr1  = (const float*)d_in[14];
  const float* Wpr2  = (const float*)d_in[15];
  const float* bpr2  = (const float*)d_in[16];
  const float* Wpo1  = (const float*)d_in[17];
  const float* bpo1  = (const float*)d_in[18];
  const float* Wpo2  = (const float*)d_in[19];
  const float* bpo2  = (const float*)d_in[20];
  float* out = (float*)d_out;

  int* flag = (int*)d_ws;
  u16* wsu  = (u16*)((char*)d_ws + 256);
  u16* bWst  = wsu;                   // 1,048,576
  u16* bWih  = wsu + 1048576UL;       // 3,145,728
  u16* bWhh  = wsu + 4194304UL;       // 6,291,456
  u16* bWpr1 = wsu + 10485760UL;      // 4,194,304
  u16* bWpr2 = wsu + 14680064UL;      // 1,048,576
  u16* bWpo1 = wsu + 15728640UL;      // 5,242,880
  u16* bWpo2 = wsu + 20971520UL;      // 1,048,576
  u16* bufX  = wsu + 22020096UL;      // 16,777,216  [B,2048]
  u16* bufSt = wsu + 38797312UL;      // 8,388,608   stoch -> later ph
  u16* bufHb = wsu + 47185920UL;      // 33,554,432  hb -> later qh
  u16* bufHn = wsu + 80740352UL;      // 33,554,432  h_new bf16
  u16* bufEm = wsu + 114294784UL;     // 8,388,608   embed bf16

  k_detect<<<dim3(1), dim3(256), 0, stream>>>((const unsigned*)isf, flag);

  Cv7 cw;
  cw.s[0] = Wst;  cw.d[0] = bWst;  cw.n4[0] = 262144L;
  cw.s[1] = Wih;  cw.d[1] = bWih;  cw.n4[1] = 786432L;
  cw.s[2] = Whh;  cw.d[2] = bWhh;  cw.n4[2] = 1572864L;
  cw.s[3] = Wpr1; cw.d[3] = bWpr1; cw.n4[3] = 1048576L;
  cw.s[4] = Wpr2; cw.d[4] = bWpr2; cw.n4[4] = 262144L;
  cw.s[5] = Wpo1; cw.d[5] = bWpo1; cw.n4[5] = 1310720L;
  cw.s[6] = Wpo2; cw.d[6] = bWpo2; cw.n4[6] = 262144L;
  k_cvtW<<<dim3(2048), dim3(256), 0, stream>>>(cw, 5505024L);

  Prep3 pp;
  pp.s[0] = stoch; pp.d[0] = bufSt; pp.n4[0] = 2097152L; pp.c4[0] = 256;  pp.doR[0] = 1;
  pp.s[1] = det;   pp.d[1] = bufHb; pp.n4[1] = 8388608L; pp.c4[1] = 1024; pp.doR[1] = 1;
  pp.s[2] = embed; pp.d[2] = bufEm; pp.n4[2] = 2097152L; pp.c4[2] = 256;  pp.doR[2] = 0;
  k_prep<<<dim3(4096), dim3(256), 0, stream>>>(pp, isf, flag);

  k_ae<<<dim3(2048), dim3(256), 0, stream>>>(pact, Wact, bact, bufX);

  // se = stoch @ Wst^T + b -> x[:, 1024:2048]
  GDesc dSe;
  dSe.A1 = bufSt; dSe.A2 = nullptr; dSe.lda1 = 1024; dSe.lda2 = 0;
  dSe.K1 = 1024; dSe.K2 = 0;
  dSe.W1 = bWst; dSe.W2 = nullptr; dSe.ldw1 = 1024; dSe.ldw2 = 0;
  dSe.bias = bst; dSe.outF = nullptr; dSe.ldoF = 0;
  dSe.outB = bufX + 1024; dSe.ldoB = 2048; dSe.actSilu = 0;
  gemm128<<<dim3(64, 8, 1), dim3(256), 0, stream>>>(dSe, dSe);

  // GRU -> h_new (f32 to out cols [0,4096), bf16 to ws); s-split grid
  gru128<<<dim3(64, 128), dim3(256), 0, stream>>>(bufX, bufHb, bWih, bWhh, bih, bhh, out, bufHn);

  // pr1 + po1 merged (z-desc): 1024 blocks co-resident
  GDesc dPr1, dPo1;
  dPr1.A1 = bufHn; dPr1.A2 = nullptr; dPr1.lda1 = 4096; dPr1.lda2 = 0;
  dPr1.K1 = 4096; dPr1.K2 = 0;
  dPr1.W1 = bWpr1; dPr1.W2 = nullptr; dPr1.ldw1 = 4096; dPr1.ldw2 = 0;
  dPr1.bias = bpr1; dPr1.outF = nullptr; dPr1.ldoF = 0;
  dPr1.outB = bufSt; dPr1.ldoB = 1024; dPr1.actSilu = 1;
  dPo1.A1 = bufHn; dPo1.A2 = bufEm; dPo1.lda1 = 4096; dPo1.lda2 = 1024;
  dPo1.K1 = 4096; dPo1.K2 = 1024;
  dPo1.W1 = bWpo1; dPo1.W2 = bWpo1 + 4096; dPo1.ldw1 = 5120; dPo1.ldw2 = 5120;
  dPo1.bias = bpo1; dPo1.outF = nullptr; dPo1.ldoF = 0;
  dPo1.outB = bufHb; dPo1.ldoB = 1024; dPo1.actSilu = 1;
  gemm128<<<dim3(64, 8, 2), dim3(256), 0, stream>>>(dPr1, dPo1);

  // pr2 + po2 merged (z-desc)
  GDesc dPr2, dPo2;
  dPr2.A1 = bufSt; dPr2.A2 = nullptr; dPr2.lda1 = 1024; dPr2.lda2 = 0;
  dPr2.K1 = 1024; dPr2.K2 = 0;
  dPr2.W1 = bWpr2; dPr2.W2 = nullptr; dPr2.ldw1 = 1024; dPr2.ldw2 = 0;
  dPr2.bias = bpr2; dPr2.outF = out + 4096; dPr2.ldoF = OUTLD;
  dPr2.outB = nullptr; dPr2.ldoB = 0; dPr2.actSilu = 0;
  dPo2.A1 = bufHb; dPo2.A2 = nullptr; dPo2.lda1 = 1024; dPo2.lda2 = 0;
  dPo2.K1 = 1024; dPo2.K2 = 0;
  dPo2.W1 = bWpo2; dPo2.W2 = nullptr; dPo2.ldw1 = 1024; dPo2.ldw2 = 0;
  dPo2.bias = bpo2; dPo2.outF = out + 6144; dPo2.ldoF = OUTLD;
  dPo2.outB = nullptr; dPo2.ldoB = 0; dPo2.actSilu = 0;
  gemm128<<<dim3(64, 8, 2), dim3(256), 0, stream>>>(dPr2, dPo2);

  k_softmax<<<dim3(1024), dim3(256), 0, stream>>>(out);
}

// Round 8
// 713.938 us; speedup vs baseline: 1.4575x; 1.0131x over previous
//
#include <hip/hip_runtime.h>

typedef unsigned short u16;
typedef short bf16x8 __attribute__((ext_vector_type(8)));
typedef float f32x4 __attribute__((ext_vector_type(4)));

#define BSZ 8192
#define OUTLD 7168

__device__ __forceinline__ u16 f2bf(float f) {
  union { float f; unsigned u; } v; v.f = f;
  unsigned r = v.u + 0x7FFFu + ((v.u >> 16) & 1u);
  return (u16)(r >> 16);
}
__device__ __forceinline__ float bf2f(u16 h) {
  union { unsigned u; float f; } v; v.u = ((unsigned)h) << 16;
  return v.f;
}
__device__ __forceinline__ float sigmoidf_(float x) { return 1.0f / (1.0f + __expf(-x)); }
__device__ __forceinline__ float tanhf_(float t) { return 2.0f / (1.0f + __expf(-2.0f * t)) - 1.0f; }

__device__ __forceinline__ void gload16(const u16* g, u16* l) {
  __builtin_amdgcn_global_load_lds(
      (const __attribute__((address_space(1))) void*)g,
      (__attribute__((address_space(3))) void*)l, 16, 0, 0);
}

// ---- is_first dtype detection ----
__global__ void k_detect(const unsigned* __restrict__ isf, int* __restrict__ flag) {
  __shared__ unsigned red;
  if (threadIdx.x == 0) red = 0u;
  __syncthreads();
  unsigned v = 0;
  for (int i = threadIdx.x; i < 2048; i += 256) v |= isf[i];
  atomicOr(&red, v);
  __syncthreads();
  if (threadIdx.x == 0)
    *flag = (((red & 0xFFFFFF00u) != 0u) && ((red & 0xFEFEFEFEu) == 0u)) ? 1 : 0;
}

__device__ __forceinline__ bool is_first_row(const void* isf, int fl, int b) {
  return fl ? (((const unsigned char*)isf)[b] != 0) : (((const int*)isf)[b] != 0);
}

// ---- merged weight cvt: 7 f32->bf16 segments, flat index ----
struct Cv7 { const float* s[7]; u16* d[7]; long n4[7]; };
__global__ void k_cvtW(Cv7 c, long total4) {
  long stride = (long)gridDim.x * blockDim.x;
  for (long i = blockIdx.x * (long)blockDim.x + threadIdx.x; i < total4; i += stride) {
    long rem = i; int k = 0;
    while (k < 6 && rem >= c.n4[k]) { rem -= c.n4[k]; ++k; }
    float4 v = ((const float4*)c.s[k])[rem];
    ushort4 o; o.x = f2bf(v.x); o.y = f2bf(v.y); o.z = f2bf(v.z); o.w = f2bf(v.w);
    ((ushort4*)c.d[k])[rem] = o;
  }
}

// ---- merged input prep: stoch/det/embed cvt (+reset) ----
struct Prep3 { const float* s[3]; u16* d[3]; long n4[3]; int c4[3]; int doR[3]; };
__global__ void k_prep(Prep3 p, const void* __restrict__ isf, const int* __restrict__ flag) {
  int fl = *flag;
  long stride = (long)gridDim.x * blockDim.x;
  long gid = blockIdx.x * (long)blockDim.x + threadIdx.x;
#pragma unroll 1
  for (int k = 0; k < 3; ++k) {
    const float4* src = (const float4*)p.s[k];
    ushort4* dst = (ushort4*)p.d[k];
    long n = p.n4[k]; int c4 = p.c4[k], doR = p.doR[k];
    for (long i = gid; i < n; i += stride) {
      float4 v = src[i];
      if (doR && is_first_row(isf, fl, (int)(i / c4))) { v.x = v.y = v.z = v.w = 0.f; }
      ushort4 o; o.x = f2bf(v.x); o.y = f2bf(v.y); o.z = f2bf(v.z); o.w = f2bf(v.w);
      dst[i] = o;
    }
  }
}

// ---- action normalize + tiny K=8 encoder -> x[:, 0:1024] ----
__global__ void k_ae(const float* __restrict__ act, const float* __restrict__ Wact,
                     const float* __restrict__ bact, u16* __restrict__ x) {
  long stride = (long)gridDim.x * blockDim.x;
  for (long t = blockIdx.x * (long)blockDim.x + threadIdx.x; t < (long)BSZ * 256; t += stride) {
    int b = (int)(t >> 8), h0 = (int)(t & 255) * 4;
    float4 a0 = ((const float4*)act)[b * 2];
    float4 a1 = ((const float4*)act)[b * 2 + 1];
    float mag = fmaxf(
        fmaxf(fmaxf(fabsf(a0.x), fabsf(a0.y)), fmaxf(fabsf(a0.z), fabsf(a0.w))),
        fmaxf(fmaxf(fabsf(a1.x), fabsf(a1.y)), fmaxf(fabsf(a1.z), fabsf(a1.w))));
    float inv = 1.0f / fmaxf(mag, 1.0f);
    ushort4 o;
    u16* op = (u16*)&o;
#pragma unroll
    for (int j = 0; j < 4; ++j) {
      int h = h0 + j;
      float4 w0 = ((const float4*)Wact)[h * 2];
      float4 w1 = ((const float4*)Wact)[h * 2 + 1];
      float dot = a0.x * w0.x + a0.y * w0.y + a0.z * w0.z + a0.w * w0.w
                + a1.x * w1.x + a1.y * w1.y + a1.z * w1.z + a1.w * w1.w;
      op[j] = f2bf(dot * inv + bact[h]);
    }
    *(ushort4*)&x[(long)b * 2048 + h0] = o;
  }
}

struct GDesc {
  const u16* A1; const u16* A2;
  int lda1, lda2, K1, K2;
  const u16* W1; const u16* W2;
  int ldw1, ldw2;
  const float* bias;
  float* outF; int ldoF;
  u16* outB; int ldoB;
  int actSilu;
};

// ======== 128x128 2-barrier GEMM (R3-proven), swizzled, desc-select ========
__global__ __launch_bounds__(256, 3) void gemm128(GDesc d0, GDesc d1) {
  const GDesc d = blockIdx.z ? d1 : d0;
  __shared__ __align__(16) u16 lsA[128 * 64];
  __shared__ __align__(16) u16 lsB[128 * 64];
  const int tid = threadIdx.x;
  const int wave = tid >> 6, lane = tid & 63;
  const int m0 = blockIdx.x * 128, n0 = blockIdx.y * 128;
  const int wr = (wave >> 1) * 64, wc = (wave & 1) * 64;
  const int lrow = lane & 15;
  const int lq = lane >> 4;
  const int lr7 = lrow & 7;
  const int grow = wave * 8 + (lane >> 3);
  const int gcol = ((lane & 7) ^ (lane >> 3)) * 8;
  const int ro0 = ((lq ^ lr7)) * 8;
  const int ro1 = (((4 | lq) ^ lr7)) * 8;

  const f32x4 z4 = {0.f, 0.f, 0.f, 0.f};
  f32x4 acc[4][4];
#pragma unroll
  for (int m = 0; m < 4; ++m)
#pragma unroll
    for (int c = 0; c < 4; ++c) acc[m][c] = z4;

#pragma unroll 1
  for (int phse = 0; phse < 2; ++phse) {
    const u16* A = phse ? d.A2 : d.A1;
    const u16* W = phse ? d.W2 : d.W1;
    const int lda = phse ? d.lda2 : d.lda1;
    const int ldw = phse ? d.ldw2 : d.ldw1;
    const int K = phse ? d.K2 : d.K1;
#pragma unroll 1
    for (int k0 = 0; k0 < K; k0 += 64) {
      __syncthreads();
#pragma unroll
      for (int i = 0; i < 4; ++i) {
        gload16(&A[(long)(m0 + i * 32 + grow) * lda + k0 + gcol], &lsA[i * 2048 + wave * 512]);
        gload16(&W[(long)(n0 + i * 32 + grow) * ldw + k0 + gcol], &lsB[i * 2048 + wave * 512]);
      }
      __syncthreads();
#pragma unroll
      for (int kk = 0; kk < 2; ++kk) {
        const int ro = kk ? ro1 : ro0;
        bf16x8 af[4], wfr[4];
#pragma unroll
        for (int m = 0; m < 4; ++m)
          af[m] = *(const bf16x8*)&lsA[(wr + m * 16 + lrow) * 64 + ro];
#pragma unroll
        for (int c = 0; c < 4; ++c)
          wfr[c] = *(const bf16x8*)&lsB[(wc + c * 16 + lrow) * 64 + ro];
#pragma unroll
        for (int m = 0; m < 4; ++m)
#pragma unroll
          for (int c = 0; c < 4; ++c)
            acc[m][c] = __builtin_amdgcn_mfma_f32_16x16x32_bf16(af[m], wfr[c], acc[m][c], 0, 0, 0);
      }
    }
  }

#pragma unroll
  for (int c = 0; c < 4; ++c) {
    const int col = n0 + wc + c * 16 + lrow;
    const float bv = d.bias ? d.bias[col] : 0.f;
#pragma unroll
    for (int m = 0; m < 4; ++m) {
      const int rowb = m0 + wr + m * 16 + (lane >> 4) * 4;
#pragma unroll
      for (int r = 0; r < 4; ++r) {
        float v = acc[m][c][r] + bv;
        if (d.actSilu) v = v * sigmoidf_(v);
        if (d.outF) d.outF[(long)(rowb + r) * d.ldoF + col] = v;
        if (d.outB) d.outB[(long)(rowb + r) * d.ldoB + col] = f2bf(v);
      }
    }
  }
}

// ======== block-diagonal GRU: 8 waves, 128 rows x 64 s-cols ========
// Per-wave acc 48 AGPR (4 waves/SIMD) at R3's MFMA density (24 MFMA / 10 gload).
__global__ __launch_bounds__(512, 4) void gru128(
    const u16* __restrict__ xbuf, const u16* __restrict__ hbuf,
    const u16* __restrict__ Wih, const u16* __restrict__ Whh,
    const float* __restrict__ bih, const float* __restrict__ bhh,
    float* __restrict__ outF, u16* __restrict__ hnew)
{
  __shared__ __align__(16) u16 lsA[128 * 64];      // 16 KB
  __shared__ __align__(16) u16 lsW[3 * 64 * 64];   // 24 KB
  const int tid = threadIdx.x;
  const int wave = tid >> 6, lane = tid & 63;
  const int wm = wave & 3;          // m-subtile (32 rows)
  const int ws = wave >> 2;         // s-half (32 cols)
  const int m0 = blockIdx.x * 128;
  const int blk = blockIdx.y >> 3;
  const int s0 = (blockIdx.y & 7) * 64;
  const int lrow = lane & 15;
  const int lq = lane >> 4;
  const int lr7 = lrow & 7;
  const int gcol = ((lane & 7) ^ (lane >> 3)) * 8;
  const int ro0 = ((lq ^ lr7)) * 8;
  const int ro1 = (((4 | lq) ^ lr7)) * 8;

  const f32x4 z4 = {0.f, 0.f, 0.f, 0.f};
  f32x4 acc[3][2][2];
#pragma unroll
  for (int g = 0; g < 3; ++g)
#pragma unroll
    for (int m = 0; m < 2; ++m)
#pragma unroll
      for (int c = 0; c < 2; ++c) acc[g][m][c] = z4;

#pragma unroll 1
  for (int phse = 0; phse < 2; ++phse) {
    const u16* A = phse ? (hbuf + blk * 512) : (xbuf + blk * 256);
    const u16* W = phse ? (Whh + (long)blk * 1536 * 512) : (Wih + (long)blk * 1536 * 256);
    const int lda = phse ? 4096 : 2048;
    const int ldw = phse ? 512 : 256;
    const int K = phse ? 512 : 256;
#pragma unroll 1
    for (int k0 = 0; k0 < K; k0 += 64) {
      __syncthreads();
      // A: 128 rows = 16 chunks of 8 rows; 8 waves x 2 rounds
#pragma unroll
      for (int r = 0; r < 2; ++r) {
        const int chunk = r * 8 + wave;
        gload16(&A[(long)(m0 + chunk * 8 + (lane >> 3)) * lda + k0 + gcol], &lsA[chunk * 512]);
      }
      // W: 3 gates x 64 rows = 24 chunks; 8 waves x 3 rounds
#pragma unroll
      for (int r = 0; r < 3; ++r) {
        const int chunk = r * 8 + wave;
        const int g = chunk >> 3;
        const int r0 = (chunk & 7) * 8;
        gload16(&W[(long)(g * 512 + s0 + r0 + (lane >> 3)) * ldw + k0 + gcol], &lsW[chunk * 512]);
      }
      __syncthreads();
#pragma unroll
      for (int kk = 0; kk < 2; ++kk) {
        const int ro = kk ? ro1 : ro0;
        bf16x8 af[2], wfr[3][2];
#pragma unroll
        for (int m = 0; m < 2; ++m)
          af[m] = *(const bf16x8*)&lsA[(wm * 32 + m * 16 + lrow) * 64 + ro];
#pragma unroll
        for (int g = 0; g < 3; ++g)
#pragma unroll
          for (int c = 0; c < 2; ++c)
            wfr[g][c] = *(const bf16x8*)&lsW[g * 4096 + (ws * 32 + c * 16 + lrow) * 64 + ro];
#pragma unroll
        for (int g = 0; g < 3; ++g)
#pragma unroll
          for (int m = 0; m < 2; ++m)
#pragma unroll
            for (int c = 0; c < 2; ++c)
              acc[g][m][c] = __builtin_amdgcn_mfma_f32_16x16x32_bf16(af[m], wfr[g][c], acc[g][m][c], 0, 0, 0);
      }
    }
  }

#pragma unroll
  for (int c = 0; c < 2; ++c) {
    const int s = s0 + ws * 32 + c * 16 + lrow;
    const int bb = blk * 1536 + s;
    const float br = bih[bb] + bhh[bb];
    const float bu = bih[bb + 512] + bhh[bb + 512];
    const float bc = bih[bb + 1024] + bhh[bb + 1024];
    const int hcol = blk * 512 + s;
#pragma unroll
    for (int m = 0; m < 2; ++m) {
      const int rowb = m0 + wm * 32 + m * 16 + lq * 4;
#pragma unroll
      for (int r = 0; r < 4; ++r) {
        const int row = rowb + r;
        const float gr = acc[0][m][c][r] + br;
        const float gu = acc[1][m][c][r] + bu;
        const float gc = acc[2][m][c][r] + bc;
        const float rr = sigmoidf_(gr);
        const float uu = sigmoidf_(gu);
        const float cand = tanhf_(rr * gc);
        const float h = bf2f(hbuf[(long)row * 4096 + hcol]);
        const float hn = (1.f - uu) * h + uu * cand;
        outF[(long)row * OUTLD + hcol] = hn;
        hnew[(long)row * 4096 + hcol] = f2bf(hn);
      }
    }
  }
}

// ---- softmax over C=32 groups + unimix ----
__global__ void k_softmax(float* __restrict__ out) {
  int t = blockIdx.x * blockDim.x + threadIdx.x;
  if (t >= BSZ * 32) return;
  int b = t >> 5, g = t & 31;
  const float* src = out + (long)b * OUTLD + 4096 + g * 32;
  float* dst = out + (long)b * OUTLD + 5120 + g * 32;
  float v[32];
#pragma unroll
  for (int i = 0; i < 8; ++i) {
    float4 q = ((const float4*)src)[i];
    v[4 * i] = q.x; v[4 * i + 1] = q.y; v[4 * i + 2] = q.z; v[4 * i + 3] = q.w;
  }
  float m = v[0];
#pragma unroll
  for (int i = 1; i < 32; ++i) m = fmaxf(m, v[i]);
  float ssum = 0.f;
#pragma unroll
  for (int i = 0; i < 32; ++i) { v[i] = __expf(v[i] - m); ssum += v[i]; }
  float inv = 0.99f / ssum;
#pragma unroll
  for (int i = 0; i < 8; ++i) {
    float4 q;
    q.x = v[4 * i] * inv + 3.125e-4f;
    q.y = v[4 * i + 1] * inv + 3.125e-4f;
    q.z = v[4 * i + 2] * inv + 3.125e-4f;
    q.w = v[4 * i + 3] * inv + 3.125e-4f;
    ((float4*)dst)[i] = q;
  }
}

extern "C" void kernel_launch(void* const* d_in, const int* in_sizes, int n_in,
                              void* d_out, int out_size, void* d_ws, size_t ws_size,
                              hipStream_t stream) {
  const float* det   = (const float*)d_in[0];
  const float* stoch = (const float*)d_in[1];
  const float* pact  = (const float*)d_in[2];
  const float* embed = (const float*)d_in[3];
  const void*  isf   = d_in[4];
  const float* Wact  = (const float*)d_in[5];
  const float* bact  = (const float*)d_in[6];
  const float* Wst   = (const float*)d_in[7];
  const float* bst   = (const float*)d_in[8];
  const float* Wih   = (const float*)d_in[9];
  const float* bih   = (const float*)d_in[10];
  const float* Whh   = (const float*)d_in[11];
  const float* bhh   = (const float*)d_in[12];
  const float* Wpr1  = (const float*)d_in[13];
  const float* bpr1  = (const float*)d_in[14];
  const float* Wpr2  = (const float*)d_in[15];
  const float* bpr2  = (const float*)d_in[16];
  const float* Wpo1  = (const float*)d_in[17];
  const float* bpo1  = (const float*)d_in[18];
  const float* Wpo2  = (const float*)d_in[19];
  const float* bpo2  = (const float*)d_in[20];
  float* out = (float*)d_out;

  int* flag = (int*)d_ws;
  u16* wsu  = (u16*)((char*)d_ws + 256);
  u16* bWst  = wsu;                   // 1,048,576
  u16* bWih  = wsu + 1048576UL;       // 3,145,728
  u16* bWhh  = wsu + 4194304UL;       // 6,291,456
  u16* bWpr1 = wsu + 10485760UL;      // 4,194,304
  u16* bWpr2 = wsu + 14680064UL;      // 1,048,576
  u16* bWpo1 = wsu + 15728640UL;      // 5,242,880
  u16* bWpo2 = wsu + 20971520UL;      // 1,048,576
  u16* bufX  = wsu + 22020096UL;      // 16,777,216  [B,2048]
  u16* bufSt = wsu + 38797312UL;      // 8,388,608   stoch -> later ph
  u16* bufHb = wsu + 47185920UL;      // 33,554,432  hb -> later qh
  u16* bufHn = wsu + 80740352UL;      // 33,554,432  h_new bf16
  u16* bufEm = wsu + 114294784UL;     // 8,388,608   embed bf16

  k_detect<<<dim3(1), dim3(256), 0, stream>>>((const unsigned*)isf, flag);

  Cv7 cw;
  cw.s[0] = Wst;  cw.d[0] = bWst;  cw.n4[0] = 262144L;
  cw.s[1] = Wih;  cw.d[1] = bWih;  cw.n4[1] = 786432L;
  cw.s[2] = Whh;  cw.d[2] = bWhh;  cw.n4[2] = 1572864L;
  cw.s[3] = Wpr1; cw.d[3] = bWpr1; cw.n4[3] = 1048576L;
  cw.s[4] = Wpr2; cw.d[4] = bWpr2; cw.n4[4] = 262144L;
  cw.s[5] = Wpo1; cw.d[5] = bWpo1; cw.n4[5] = 1310720L;
  cw.s[6] = Wpo2; cw.d[6] = bWpo2; cw.n4[6] = 262144L;
  k_cvtW<<<dim3(2048), dim3(256), 0, stream>>>(cw, 5505024L);

  Prep3 pp;
  pp.s[0] = stoch; pp.d[0] = bufSt; pp.n4[0] = 2097152L; pp.c4[0] = 256;  pp.doR[0] = 1;
  pp.s[1] = det;   pp.d[1] = bufHb; pp.n4[1] = 8388608L; pp.c4[1] = 1024; pp.doR[1] = 1;
  pp.s[2] = embed; pp.d[2] = bufEm; pp.n4[2] = 2097152L; pp.c4[2] = 256;  pp.doR[2] = 0;
  k_prep<<<dim3(4096), dim3(256), 0, stream>>>(pp, isf, flag);

  k_ae<<<dim3(2048), dim3(256), 0, stream>>>(pact, Wact, bact, bufX);

  // se = stoch @ Wst^T + b -> x[:, 1024:2048]
  GDesc dSe;
  dSe.A1 = bufSt; dSe.A2 = nullptr; dSe.lda1 = 1024; dSe.lda2 = 0;
  dSe.K1 = 1024; dSe.K2 = 0;
  dSe.W1 = bWst; dSe.W2 = nullptr; dSe.ldw1 = 1024; dSe.ldw2 = 0;
  dSe.bias = bst; dSe.outF = nullptr; dSe.ldoF = 0;
  dSe.outB = bufX + 1024; dSe.ldoB = 2048; dSe.actSilu = 0;
  gemm128<<<dim3(64, 8, 1), dim3(256), 0, stream>>>(dSe, dSe);

  // GRU -> h_new (f32 to out cols [0,4096), bf16 to ws); 8-wave blocks
  gru128<<<dim3(64, 64), dim3(512), 0, stream>>>(bufX, bufHb, bWih, bWhh, bih, bhh, out, bufHn);

  // pr1 + po1 merged (z-desc)
  GDesc dPr1, dPo1;
  dPr1.A1 = bufHn; dPr1.A2 = nullptr; dPr1.lda1 = 4096; dPr1.lda2 = 0;
  dPr1.K1 = 4096; dPr1.K2 = 0;
  dPr1.W1 = bWpr1; dPr1.W2 = nullptr; dPr1.ldw1 = 4096; dPr1.ldw2 = 0;
  dPr1.bias = bpr1; dPr1.outF = nullptr; dPr1.ldoF = 0;
  dPr1.outB = bufSt; dPr1.ldoB = 1024; dPr1.actSilu = 1;
  dPo1.A1 = bufHn; dPo1.A2 = bufEm; dPo1.lda1 = 4096; dPo1.lda2 = 1024;
  dPo1.K1 = 4096; dPo1.K2 = 1024;
  dPo1.W1 = bWpo1; dPo1.W2 = bWpo1 + 4096; dPo1.ldw1 = 5120; dPo1.ldw2 = 5120;
  dPo1.bias = bpo1; dPo1.outF = nullptr; dPo1.ldoF = 0;
  dPo1.outB = bufHb; dPo1.ldoB = 1024; dPo1.actSilu = 1;
  gemm128<<<dim3(64, 8, 2), dim3(256), 0, stream>>>(dPr1, dPo1);

  // pr2 + po2 merged (z-desc)
  GDesc dPr2, dPo2;
  dPr2.A1 = bufSt; dPr2.A2 = nullptr; dPr2.lda1 = 1024; dPr2.lda2 = 0;
  dPr2.K1 = 1024; dPr2.K2 = 0;
  dPr2.W1 = bWpr2; dPr2.W2 = nullptr; dPr2.ldw1 = 1024; dPr2.ldw2 = 0;
  dPr2.bias = bpr2; dPr2.outF = out + 4096; dPr2.ldoF = OUTLD;
  dPr2.outB = nullptr; dPr2.ldoB = 0; dPr2.actSilu = 0;
  dPo2.A1 = bufHb; dPo2.A2 = nullptr; dPo2.lda1 = 1024; dPo2.lda2 = 0;
  dPo2.K1 = 1024; dPo2.K2 = 0;
  dPo2.W1 = bWpo2; dPo2.W2 = nullptr; dPo2.ldw1 = 1024; dPo2.ldw2 = 0;
  dPo2.bias = bpo2; dPo2.outF = out + 6144; dPo2.ldoF = OUTLD;
  dPo2.outB = nullptr; dPo2.ldoB = 0; dPo2.actSilu = 0;
  gemm128<<<dim3(64, 8, 2), dim3(256), 0, stream>>>(dPr2, dPo2);

  k_softmax<<<dim3(1024), dim3(256), 0, stream>>>(out);
}

// Round 9
// 670.239 us; speedup vs baseline: 1.5525x; 1.0652x over previous
//
#include <hip/hip_runtime.h>

typedef unsigned short u16;
typedef short bf16x8 __attribute__((ext_vector_type(8)));
typedef float f32x4 __attribute__((ext_vector_type(4)));

#define BSZ 8192
#define OUTLD 7168

__device__ __forceinline__ u16 f2bf(float f) {
  union { float f; unsigned u; } v; v.f = f;
  unsigned r = v.u + 0x7FFFu + ((v.u >> 16) & 1u);
  return (u16)(r >> 16);
}
__device__ __forceinline__ float bf2f(u16 h) {
  union { unsigned u; float f; } v; v.u = ((unsigned)h) << 16;
  return v.f;
}
__device__ __forceinline__ float sigmoidf_(float x) { return 1.0f / (1.0f + __expf(-x)); }
__device__ __forceinline__ float tanhf_(float t) { return 2.0f / (1.0f + __expf(-2.0f * t)) - 1.0f; }

__device__ __forceinline__ void gload16(const u16* g, u16* l) {
  __builtin_amdgcn_global_load_lds(
      (const __attribute__((address_space(1))) void*)g,
      (__attribute__((address_space(3))) void*)l, 16, 0, 0);
}

// ---- is_first dtype detection ----
__global__ void k_detect(const unsigned* __restrict__ isf, int* __restrict__ flag) {
  __shared__ unsigned red;
  if (threadIdx.x == 0) red = 0u;
  __syncthreads();
  unsigned v = 0;
  for (int i = threadIdx.x; i < 2048; i += 256) v |= isf[i];
  atomicOr(&red, v);
  __syncthreads();
  if (threadIdx.x == 0)
    *flag = (((red & 0xFFFFFF00u) != 0u) && ((red & 0xFEFEFEFEu) == 0u)) ? 1 : 0;
}

__device__ __forceinline__ bool is_first_row(const void* isf, int fl, int b) {
  return fl ? (((const unsigned char*)isf)[b] != 0) : (((const int*)isf)[b] != 0);
}

// ---- plain weight cvt: 5 f32->bf16 segments, flat index ----
struct Cv5 { const float* s[5]; u16* d[5]; long n4[5]; };
__global__ void k_cvtW(Cv5 c, long total4) {
  long stride = (long)gridDim.x * blockDim.x;
  for (long i = blockIdx.x * (long)blockDim.x + threadIdx.x; i < total4; i += stride) {
    long rem = i; int k = 0;
    while (k < 4 && rem >= c.n4[k]) { rem -= c.n4[k]; ++k; }
    float4 v = ((const float4*)c.s[k])[rem];
    ushort4 o; o.x = f2bf(v.x); o.y = f2bf(v.y); o.z = f2bf(v.z); o.w = f2bf(v.w);
    ((ushort4*)c.d[k])[rem] = o;
  }
}

// ---- GRU weight cvt with gate-interleave row permutation (R4-verified) ----
// dst row (within blk): rP = (s>>4)*48 + g*16 + (s&15), from src row g*512+s.
// Handles both Wih (ldk=256) and Whh (ldk=512) in one launch.
__global__ void k_cvt_gruW(const float* __restrict__ sIh, u16* __restrict__ dIh,
                           const float* __restrict__ sHh, u16* __restrict__ dHh) {
  const long nIh = 393216L, total = 1179648L;  // in 8-elem units
  long stride = (long)gridDim.x * blockDim.x;
  for (long i = blockIdx.x * (long)blockDim.x + threadIdx.x; i < total; i += stride) {
    const float* src; u16* dst; int ldk; long rel;
    if (i < nIh) { src = sIh; dst = dIh; ldk = 256; rel = i; }
    else         { src = sHh; dst = dHh; ldk = 512; rel = i - nIh; }
    int kc = ldk >> 3;
    int j = (int)(rel % kc); long row = rel / kc;
    long blk = row / 1536; int rP = (int)(row % 1536);
    int sHi = rP / 48, rem = rP % 48, g = rem >> 4, sLo = rem & 15;
    int srow = g * 512 + sHi * 16 + sLo;
    const float* s = src + (blk * 1536 + srow) * (long)ldk + j * 8;
    float4 v0 = ((const float4*)s)[0], v1 = ((const float4*)s)[1];
    ushort4 o0; o0.x = f2bf(v0.x); o0.y = f2bf(v0.y); o0.z = f2bf(v0.z); o0.w = f2bf(v0.w);
    ushort4 o1; o1.x = f2bf(v1.x); o1.y = f2bf(v1.y); o1.z = f2bf(v1.z); o1.w = f2bf(v1.w);
    ((ushort4*)(dst + rel * 8))[0] = o0;
    ((ushort4*)(dst + rel * 8))[1] = o1;
  }
}

// ---- merged input prep: stoch/det/embed cvt (+reset) ----
struct Prep3 { const float* s[3]; u16* d[3]; long n4[3]; int c4[3]; int doR[3]; };
__global__ void k_prep(Prep3 p, const void* __restrict__ isf, const int* __restrict__ flag) {
  int fl = *flag;
  long stride = (long)gridDim.x * blockDim.x;
  long gid = blockIdx.x * (long)blockDim.x + threadIdx.x;
#pragma unroll 1
  for (int k = 0; k < 3; ++k) {
    const float4* src = (const float4*)p.s[k];
    ushort4* dst = (ushort4*)p.d[k];
    long n = p.n4[k]; int c4 = p.c4[k], doR = p.doR[k];
    for (long i = gid; i < n; i += stride) {
      float4 v = src[i];
      if (doR && is_first_row(isf, fl, (int)(i / c4))) { v.x = v.y = v.z = v.w = 0.f; }
      ushort4 o; o.x = f2bf(v.x); o.y = f2bf(v.y); o.z = f2bf(v.z); o.w = f2bf(v.w);
      dst[i] = o;
    }
  }
}

// ---- action normalize + tiny K=8 encoder -> x[:, 0:1024] ----
__global__ void k_ae(const float* __restrict__ act, const float* __restrict__ Wact,
                     const float* __restrict__ bact, u16* __restrict__ x) {
  long stride = (long)gridDim.x * blockDim.x;
  for (long t = blockIdx.x * (long)blockDim.x + threadIdx.x; t < (long)BSZ * 256; t += stride) {
    int b = (int)(t >> 8), h0 = (int)(t & 255) * 4;
    float4 a0 = ((const float4*)act)[b * 2];
    float4 a1 = ((const float4*)act)[b * 2 + 1];
    float mag = fmaxf(
        fmaxf(fmaxf(fabsf(a0.x), fabsf(a0.y)), fmaxf(fabsf(a0.z), fabsf(a0.w))),
        fmaxf(fmaxf(fabsf(a1.x), fabsf(a1.y)), fmaxf(fabsf(a1.z), fabsf(a1.w))));
    float inv = 1.0f / fmaxf(mag, 1.0f);
    ushort4 o;
    u16* op = (u16*)&o;
#pragma unroll
    for (int j = 0; j < 4; ++j) {
      int h = h0 + j;
      float4 w0 = ((const float4*)Wact)[h * 2];
      float4 w1 = ((const float4*)Wact)[h * 2 + 1];
      float dot = a0.x * w0.x + a0.y * w0.y + a0.z * w0.z + a0.w * w0.w
                + a1.x * w1.x + a1.y * w1.y + a1.z * w1.z + a1.w * w1.w;
      op[j] = f2bf(dot * inv + bact[h]);
    }
    *(ushort4*)&x[(long)b * 2048 + h0] = o;
  }
}

struct GDesc {
  const u16* A1; const u16* A2;
  int lda1, lda2, K1, K2;
  const u16* W1; const u16* W2;
  int ldw1, ldw2;
  const float* bias;
  float* outF; int ldoF;
  u16* outB; int ldoB;
  int actSilu;
};

// ======== 128x128 2-barrier GEMM (R3-proven), swizzled, desc-select ========
__global__ __launch_bounds__(256, 3) void gemm128(GDesc d0, GDesc d1) {
  const GDesc d = blockIdx.z ? d1 : d0;
  __shared__ __align__(16) u16 lsA[128 * 64];
  __shared__ __align__(16) u16 lsB[128 * 64];
  const int tid = threadIdx.x;
  const int wave = tid >> 6, lane = tid & 63;
  const int m0 = blockIdx.x * 128, n0 = blockIdx.y * 128;
  const int wr = (wave >> 1) * 64, wc = (wave & 1) * 64;
  const int lrow = lane & 15;
  const int lq = lane >> 4;
  const int lr7 = lrow & 7;
  const int grow = wave * 8 + (lane >> 3);
  const int gcol = ((lane & 7) ^ (lane >> 3)) * 8;
  const int ro0 = ((lq ^ lr7)) * 8;
  const int ro1 = (((4 | lq) ^ lr7)) * 8;

  const f32x4 z4 = {0.f, 0.f, 0.f, 0.f};
  f32x4 acc[4][4];
#pragma unroll
  for (int m = 0; m < 4; ++m)
#pragma unroll
    for (int c = 0; c < 4; ++c) acc[m][c] = z4;

#pragma unroll 1
  for (int phse = 0; phse < 2; ++phse) {
    const u16* A = phse ? d.A2 : d.A1;
    const u16* W = phse ? d.W2 : d.W1;
    const int lda = phse ? d.lda2 : d.lda1;
    const int ldw = phse ? d.ldw2 : d.ldw1;
    const int K = phse ? d.K2 : d.K1;
#pragma unroll 1
    for (int k0 = 0; k0 < K; k0 += 64) {
      __syncthreads();
#pragma unroll
      for (int i = 0; i < 4; ++i) {
        gload16(&A[(long)(m0 + i * 32 + grow) * lda + k0 + gcol], &lsA[i * 2048 + wave * 512]);
        gload16(&W[(long)(n0 + i * 32 + grow) * ldw + k0 + gcol], &lsB[i * 2048 + wave * 512]);
      }
      __syncthreads();
#pragma unroll
      for (int kk = 0; kk < 2; ++kk) {
        const int ro = kk ? ro1 : ro0;
        bf16x8 af[4], wfr[4];
#pragma unroll
        for (int m = 0; m < 4; ++m)
          af[m] = *(const bf16x8*)&lsA[(wr + m * 16 + lrow) * 64 + ro];
#pragma unroll
        for (int c = 0; c < 4; ++c)
          wfr[c] = *(const bf16x8*)&lsB[(wc + c * 16 + lrow) * 64 + ro];
#pragma unroll
        for (int m = 0; m < 4; ++m)
#pragma unroll
          for (int c = 0; c < 4; ++c)
            acc[m][c] = __builtin_amdgcn_mfma_f32_16x16x32_bf16(af[m], wfr[c], acc[m][c], 0, 0, 0);
      }
    }
  }

#pragma unroll
  for (int c = 0; c < 4; ++c) {
    const int col = n0 + wc + c * 16 + lrow;
    const float bv = d.bias ? d.bias[col] : 0.f;
#pragma unroll
    for (int m = 0; m < 4; ++m) {
      const int rowb = m0 + wr + m * 16 + (lane >> 4) * 4;
#pragma unroll
      for (int r = 0; r < 4; ++r) {
        float v = acc[m][c][r] + bv;
        if (d.actSilu) v = v * sigmoidf_(v);
        if (d.outF) d.outF[(long)(rowb + r) * d.ldoF + col] = v;
        if (d.outB) d.outB[(long)(rowb + r) * d.ldoB + col] = f2bf(v);
      }
    }
  }
}

// ======== block-diagonal GRU gru96: wave = 64 rows x 48 permuted cols ========
// Density 24 MFMA : 14 ds_read per wave-K-step; acc 48 AGPR -> 4 waves/SIMD.
// Weights pre-permuted rP = (s>>4)*48 + g*16 + (s&15): wave's 3 n-frags are
// gates {r,u,c} of one 16-col s-group -> fused epilogue.
__global__ __launch_bounds__(256, 4) void gru96(
    const u16* __restrict__ xbuf, const u16* __restrict__ hbuf,
    const u16* __restrict__ WihP, const u16* __restrict__ WhhP,
    const float* __restrict__ bih, const float* __restrict__ bhh,
    float* __restrict__ outF, u16* __restrict__ hnew)
{
  __shared__ __align__(16) u16 lsA[128 * 64];   // 16 KB
  __shared__ __align__(16) u16 lsW[96 * 64];    // 12 KB
  const int tid = threadIdx.x;
  const int wave = tid >> 6, lane = tid & 63;
  const int wm = wave >> 1;          // 0..1: 64-row half
  const int wn = wave & 1;           // 0..1: 48-col half
  const int m0 = blockIdx.x * 128;
  const int blk = blockIdx.y >> 4;
  const int sp = blockIdx.y & 15;    // 96-permuted-row slice = 32 s-cols
  const int lrow = lane & 15;
  const int lq = lane >> 4;
  const int lr7 = lane & 7;
  const int gcol = ((lane & 7) ^ (lane >> 3)) * 8;
  const int ro0 = ((lq ^ lr7)) * 8;
  const int ro1 = (((4 | lq) ^ lr7)) * 8;

  const f32x4 z4 = {0.f, 0.f, 0.f, 0.f};
  f32x4 acc[4][3];
#pragma unroll
  for (int m = 0; m < 4; ++m)
#pragma unroll
    for (int g = 0; g < 3; ++g) acc[m][g] = z4;

#pragma unroll 1
  for (int phse = 0; phse < 2; ++phse) {
    const u16* A = phse ? (hbuf + blk * 512) : (xbuf + blk * 256);
    const u16* W = phse ? (WhhP + (long)blk * 786432 + sp * 49152)
                        : (WihP + (long)blk * 393216 + sp * 24576);
    const int lda = phse ? 4096 : 2048;
    const int ldw = phse ? 512 : 256;
    const int K = phse ? 512 : 256;
#pragma unroll 1
    for (int k0 = 0; k0 < K; k0 += 64) {
      __syncthreads();
      // A: 128 rows = 16 chunks of 8; 4 waves x 4 rounds
#pragma unroll
      for (int r = 0; r < 4; ++r) {
        const int chunk = r * 4 + wave;
        gload16(&A[(long)(m0 + chunk * 8 + (lane >> 3)) * lda + k0 + gcol], &lsA[chunk * 512]);
      }
      // W: 96 permuted rows = 12 chunks of 8; 4 waves x 3 rounds
#pragma unroll
      for (int r = 0; r < 3; ++r) {
        const int chunk = r * 4 + wave;
        gload16(&W[(long)(chunk * 8 + (lane >> 3)) * ldw + k0 + gcol], &lsW[chunk * 512]);
      }
      __syncthreads();
#pragma unroll
      for (int kk = 0; kk < 2; ++kk) {
        const int ro = kk ? ro1 : ro0;
        bf16x8 af[4], wf[3];
#pragma unroll
        for (int m = 0; m < 4; ++m)
          af[m] = *(const bf16x8*)&lsA[(wm * 64 + m * 16 + lrow) * 64 + ro];
#pragma unroll
        for (int g = 0; g < 3; ++g)
          wf[g] = *(const bf16x8*)&lsW[(wn * 48 + g * 16 + lrow) * 64 + ro];
#pragma unroll
        for (int m = 0; m < 4; ++m)
#pragma unroll
          for (int g = 0; g < 3; ++g)
            acc[m][g] = __builtin_amdgcn_mfma_f32_16x16x32_bf16(af[m], wf[g], acc[m][g], 0, 0, 0);
      }
    }
  }

  // fused GRU epilogue: this thread owns s = sp*32 + wn*16 + lrow
  const int s = sp * 32 + wn * 16 + lrow;
  const int col = blk * 512 + s;
  const long bb = (long)blk * 1536 + s;
  const float br = bih[bb] + bhh[bb];
  const float bu = bih[bb + 512] + bhh[bb + 512];
  const float bc = bih[bb + 1024] + bhh[bb + 1024];
#pragma unroll
  for (int m = 0; m < 4; ++m) {
    const int rowb = m0 + wm * 64 + m * 16 + lq * 4;
#pragma unroll
    for (int r = 0; r < 4; ++r) {
      const int row = rowb + r;
      const float gr = acc[m][0][r] + br;
      const float gu = acc[m][1][r] + bu;
      const float gc = acc[m][2][r] + bc;
      const float rr = sigmoidf_(gr);
      const float uu = sigmoidf_(gu);
      const float cand = tanhf_(rr * gc);
      const float h = bf2f(hbuf[(long)row * 4096 + col]);
      const float hn = (1.f - uu) * h + uu * cand;
      outF[(long)row * OUTLD + col] = hn;
      hnew[(long)row * 4096 + col] = f2bf(hn);
    }
  }
}

// ---- softmax over C=32 groups + unimix ----
__global__ void k_softmax(float* __restrict__ out) {
  int t = blockIdx.x * blockDim.x + threadIdx.x;
  if (t >= BSZ * 32) return;
  int b = t >> 5, g = t & 31;
  const float* src = out + (long)b * OUTLD + 4096 + g * 32;
  float* dst = out + (long)b * OUTLD + 5120 + g * 32;
  float v[32];
#pragma unroll
  for (int i = 0; i < 8; ++i) {
    float4 q = ((const float4*)src)[i];
    v[4 * i] = q.x; v[4 * i + 1] = q.y; v[4 * i + 2] = q.z; v[4 * i + 3] = q.w;
  }
  float m = v[0];
#pragma unroll
  for (int i = 1; i < 32; ++i) m = fmaxf(m, v[i]);
  float ssum = 0.f;
#pragma unroll
  for (int i = 0; i < 32; ++i) { v[i] = __expf(v[i] - m); ssum += v[i]; }
  float inv = 0.99f / ssum;
#pragma unroll
  for (int i = 0; i < 8; ++i) {
    float4 q;
    q.x = v[4 * i] * inv + 3.125e-4f;
    q.y = v[4 * i + 1] * inv + 3.125e-4f;
    q.z = v[4 * i + 2] * inv + 3.125e-4f;
    q.w = v[4 * i + 3] * inv + 3.125e-4f;
    ((float4*)dst)[i] = q;
  }
}

extern "C" void kernel_launch(void* const* d_in, const int* in_sizes, int n_in,
                              void* d_out, int out_size, void* d_ws, size_t ws_size,
                              hipStream_t stream) {
  const float* det   = (const float*)d_in[0];
  const float* stoch = (const float*)d_in[1];
  const float* pact  = (const float*)d_in[2];
  const float* embed = (const float*)d_in[3];
  const void*  isf   = d_in[4];
  const float* Wact  = (const float*)d_in[5];
  const float* bact  = (const float*)d_in[6];
  const float* Wst   = (const float*)d_in[7];
  const float* bst   = (const float*)d_in[8];
  const float* Wih   = (const float*)d_in[9];
  const float* bih   = (const float*)d_in[10];
  const float* Whh   = (const float*)d_in[11];
  const float* bhh   = (const float*)d_in[12];
  const float* Wpr1  = (const float*)d_in[13];
  const float* bpr1  = (const float*)d_in[14];
  const float* Wpr2  = (const float*)d_in[15];
  const float* bpr2  = (const float*)d_in[16];
  const float* Wpo1  = (const float*)d_in[17];
  const float* bpo1  = (const float*)d_in[18];
  const float* Wpo2  = (const float*)d_in[19];
  const float* bpo2  = (const float*)d_in[20];
  float* out = (float*)d_out;

  int* flag = (int*)d_ws;
  u16* wsu  = (u16*)((char*)d_ws + 256);
  u16* bWst  = wsu;                   // 1,048,576
  u16* bWihP = wsu + 1048576UL;       // 3,145,728 (permuted)
  u16* bWhhP = wsu + 4194304UL;       // 6,291,456 (permuted)
  u16* bWpr1 = wsu + 10485760UL;      // 4,194,304
  u16* bWpr2 = wsu + 14680064UL;      // 1,048,576
  u16* bWpo1 = wsu + 15728640UL;      // 5,242,880
  u16* bWpo2 = wsu + 20971520UL;      // 1,048,576
  u16* bufX  = wsu + 22020096UL;      // 16,777,216  [B,2048]
  u16* bufSt = wsu + 38797312UL;      // 8,388,608   stoch -> later ph
  u16* bufHb = wsu + 47185920UL;      // 33,554,432  hb -> later qh
  u16* bufHn = wsu + 80740352UL;      // 33,554,432  h_new bf16
  u16* bufEm = wsu + 114294784UL;     // 8,388,608   embed bf16

  k_detect<<<dim3(1), dim3(256), 0, stream>>>((const unsigned*)isf, flag);

  Cv5 cw;
  cw.s[0] = Wst;  cw.d[0] = bWst;  cw.n4[0] = 262144L;
  cw.s[1] = Wpr1; cw.d[1] = bWpr1; cw.n4[1] = 1048576L;
  cw.s[2] = Wpr2; cw.d[2] = bWpr2; cw.n4[2] = 262144L;
  cw.s[3] = Wpo1; cw.d[3] = bWpo1; cw.n4[3] = 1310720L;
  cw.s[4] = Wpo2; cw.d[4] = bWpo2; cw.n4[4] = 262144L;
  k_cvtW<<<dim3(2048), dim3(256), 0, stream>>>(cw, 3145728L);

  k_cvt_gruW<<<dim3(2048), dim3(256), 0, stream>>>(Wih, bWihP, Whh, bWhhP);

  Prep3 pp;
  pp.s[0] = stoch; pp.d[0] = bufSt; pp.n4[0] = 2097152L; pp.c4[0] = 256;  pp.doR[0] = 1;
  pp.s[1] = det;   pp.d[1] = bufHb; pp.n4[1] = 8388608L; pp.c4[1] = 1024; pp.doR[1] = 1;
  pp.s[2] = embed; pp.d[2] = bufEm; pp.n4[2] = 2097152L; pp.c4[2] = 256;  pp.doR[2] = 0;
  k_prep<<<dim3(4096), dim3(256), 0, stream>>>(pp, isf, flag);

  k_ae<<<dim3(2048), dim3(256), 0, stream>>>(pact, Wact, bact, bufX);

  // se = stoch @ Wst^T + b -> x[:, 1024:2048]
  GDesc dSe;
  dSe.A1 = bufSt; dSe.A2 = nullptr; dSe.lda1 = 1024; dSe.lda2 = 0;
  dSe.K1 = 1024; dSe.K2 = 0;
  dSe.W1 = bWst; dSe.W2 = nullptr; dSe.ldw1 = 1024; dSe.ldw2 = 0;
  dSe.bias = bst; dSe.outF = nullptr; dSe.ldoF = 0;
  dSe.outB = bufX + 1024; dSe.ldoB = 2048; dSe.actSilu = 0;
  gemm128<<<dim3(64, 8, 1), dim3(256), 0, stream>>>(dSe, dSe);

  // GRU -> h_new (f32 to out cols [0,4096), bf16 to ws)
  gru96<<<dim3(64, 128), dim3(256), 0, stream>>>(bufX, bufHb, bWihP, bWhhP,
                                                 bih, bhh, out, bufHn);

  // pr1 + po1 merged (z-desc)
  GDesc dPr1, dPo1;
  dPr1.A1 = bufHn; dPr1.A2 = nullptr; dPr1.lda1 = 4096; dPr1.lda2 = 0;
  dPr1.K1 = 4096; dPr1.K2 = 0;
  dPr1.W1 = bWpr1; dPr1.W2 = nullptr; dPr1.ldw1 = 4096; dPr1.ldw2 = 0;
  dPr1.bias = bpr1; dPr1.outF = nullptr; dPr1.ldoF = 0;
  dPr1.outB = bufSt; dPr1.ldoB = 1024; dPr1.actSilu = 1;
  dPo1.A1 = bufHn; dPo1.A2 = bufEm; dPo1.lda1 = 4096; dPo1.lda2 = 1024;
  dPo1.K1 = 4096; dPo1.K2 = 1024;
  dPo1.W1 = bWpo1; dPo1.W2 = bWpo1 + 4096; dPo1.ldw1 = 5120; dPo1.ldw2 = 5120;
  dPo1.bias = bpo1; dPo1.outF = nullptr; dPo1.ldoF = 0;
  dPo1.outB = bufHb; dPo1.ldoB = 1024; dPo1.actSilu = 1;
  gemm128<<<dim3(64, 8, 2), dim3(256), 0, stream>>>(dPr1, dPo1);

  // pr2 + po2 merged (z-desc)
  GDesc dPr2, dPo2;
  dPr2.A1 = bufSt; dPr2.A2 = nullptr; dPr2.lda1 = 1024; dPr2.lda2 = 0;
  dPr2.K1 = 1024; dPr2.K2 = 0;
  dPr2.W1 = bWpr2; dPr2.W2 = nullptr; dPr2.ldw1 = 1024; dPr2.ldw2 = 0;
  dPr2.bias = bpr2; dPr2.outF = out + 4096; dPr2.ldoF = OUTLD;
  dPr2.outB = nullptr; dPr2.ldoB = 0; dPr2.actSilu = 0;
  dPo2.A1 = bufHb; dPo2.A2 = nullptr; dPo2.lda1 = 1024; dPo2.lda2 = 0;
  dPo2.K1 = 1024; dPo2.K2 = 0;
  dPo2.W1 = bWpo2; dPo2.W2 = nullptr; dPo2.ldw1 = 1024; dPo2.ldw2 = 0;
  dPo2.bias = bpo2; dPo2.outF = out + 6144; dPo2.ldoF = OUTLD;
  dPo2.outB = nullptr; dPo2.ldoB = 0; dPo2.actSilu = 0;
  gemm128<<<dim3(64, 8, 2), dim3(256), 0, stream>>>(dPr2, dPo2);

  k_softmax<<<dim3(1024), dim3(256), 0, stream>>>(out);
}